// Round 2
// baseline (457.559 us; speedup 1.0000x reference)
//
#include <hip/hip_runtime.h>

typedef short s16x8 __attribute__((ext_vector_type(8)));
typedef float f32x4 __attribute__((ext_vector_type(4)));

__device__ __forceinline__ float b2f(unsigned short u) {
    union { unsigned int i; float f; } v;
    v.i = ((unsigned int)u) << 16;
    return v.f;
}
__device__ __forceinline__ unsigned short f2b(float f) {
    unsigned int x = __builtin_bit_cast(unsigned int, f);
    unsigned int r = (x + 0x7fffu + ((x >> 16) & 1u)) >> 16;
    return (unsigned short)r;
}

// load 8 consecutive elements as bf16 fragment
__device__ __forceinline__ s16x8 load8_bf16(const unsigned short* p) {
    return *(const s16x8*)p;
}
__device__ __forceinline__ s16x8 load8_bf16(const float* p) {
    float4 a = *(const float4*)p;
    float4 b = *(const float4*)(p + 4);
    s16x8 r;
    r[0] = (short)f2b(a.x); r[1] = (short)f2b(a.y);
    r[2] = (short)f2b(a.z); r[3] = (short)f2b(a.w);
    r[4] = (short)f2b(b.x); r[5] = (short)f2b(b.y);
    r[6] = (short)f2b(b.z); r[7] = (short)f2b(b.w);
    return r;
}
__device__ __forceinline__ void store_c(unsigned short* C, size_t idx, float v) { C[idx] = f2b(v); }
__device__ __forceinline__ void store_c(float* C, size_t idx, float v) { C[idx] = v; }

// ---------------------------------------------------------------------------
// NT GEMM: C[M][N] = A[M][K] * B[N][K]^T + bias[N]; bf16 MFMA, fp32 accum.
// A/B may be fp32 (converted during staging) or bf16. 128x128 tile, BK=64,
// 256 threads (4 waves, 2x2 of 64x64), 16x16x32 MFMA.
// ---------------------------------------------------------------------------
template <typename TA, typename TB, typename TC>
__global__ __launch_bounds__(256) void gemm_bias_nt(
    const TA* __restrict__ A,
    const TB* __restrict__ Bm,
    const float* __restrict__ bias,
    TC* __restrict__ C,
    int M, int N, int K)
{
    __shared__ __attribute__((aligned(16))) unsigned short As[128 * 72];
    __shared__ __attribute__((aligned(16))) unsigned short Bs[128 * 72];
    const int t = threadIdx.x;
    const int wave = t >> 6, lane = t & 63;
    const int m0 = blockIdx.x * 128, n0 = blockIdx.y * 128;
    const int wm = (wave >> 1) * 64, wn = (wave & 1) * 64;
    const int lr = lane & 15, lq = lane >> 4;

    f32x4 acc[4][4];
#pragma unroll
    for (int i = 0; i < 4; ++i)
#pragma unroll
        for (int j = 0; j < 4; ++j) acc[i][j] = (f32x4){0.f, 0.f, 0.f, 0.f};

    for (int k0 = 0; k0 < K; k0 += 64) {
        __syncthreads();
#pragma unroll
        for (int p = 0; p < 4; ++p) {
            int c = t + p * 256;
            int row = c >> 3, c8 = (c & 7) << 3;
            *(s16x8*)&As[row * 72 + c8] = load8_bf16(&A[(size_t)(m0 + row) * K + k0 + c8]);
            *(s16x8*)&Bs[row * 72 + c8] = load8_bf16(&Bm[(size_t)(n0 + row) * K + k0 + c8]);
        }
        __syncthreads();
#pragma unroll
        for (int kk = 0; kk < 64; kk += 32) {
            s16x8 af[4], bf[4];
#pragma unroll
            for (int i = 0; i < 4; ++i)
                af[i] = *(const s16x8*)&As[(wm + i * 16 + lr) * 72 + kk + lq * 8];
#pragma unroll
            for (int j = 0; j < 4; ++j)
                bf[j] = *(const s16x8*)&Bs[(wn + j * 16 + lr) * 72 + kk + lq * 8];
#pragma unroll
            for (int i = 0; i < 4; ++i)
#pragma unroll
                for (int j = 0; j < 4; ++j)
                    acc[i][j] = __builtin_amdgcn_mfma_f32_16x16x32_bf16(af[i], bf[j], acc[i][j], 0, 0, 0);
        }
    }
    // Epilogue. C/D layout: row = lq*4+r (A index), col = lr (B index).
#pragma unroll
    for (int j = 0; j < 4; ++j) {
        int col = n0 + wn + j * 16 + lr;
        float bv = bias[col];
#pragma unroll
        for (int i = 0; i < 4; ++i) {
            int rowb = m0 + wm + i * 16 + lq * 4;
#pragma unroll
            for (int r = 0; r < 4; ++r)
                store_c(C, (size_t)(rowb + r) * N + col, acc[i][j][r] + bv);
        }
    }
}

// ---------------------------------------------------------------------------
// q_scaled = (q/||q||_head + query_embedding[h]) * softplus(temperature[h])
// One token per block; 16 lanes per head (4 elems/lane), in-place (bf16 ws).
// ---------------------------------------------------------------------------
__global__ __launch_bounds__(256) void qscale_kernel(
    unsigned short* __restrict__ Q,
    const float* __restrict__ temp,
    const float* __restrict__ qe)
{
    const int tok = blockIdx.x, t = threadIdx.x;
    const int h = t >> 4;
    const int c0 = t << 2;
    size_t base = (size_t)tok * 1024 + c0;
    ushort4 raw = *(const ushort4*)&Q[base];
    float v0 = b2f(raw.x), v1 = b2f(raw.y), v2 = b2f(raw.z), v3 = b2f(raw.w);
    float ss = v0 * v0 + v1 * v1 + v2 * v2 + v3 * v3;
    ss += __shfl_xor(ss, 1); ss += __shfl_xor(ss, 2);
    ss += __shfl_xor(ss, 4); ss += __shfl_xor(ss, 8);
    float rn = rsqrtf(ss);
    float tv = temp[h];
    float sp = (tv > 20.f) ? tv : log1pf(__expf(tv));
    int d0 = c0 & 63;
    ushort4 o;
    o.x = f2b((v0 * rn + qe[h * 64 + d0 + 0]) * sp);
    o.y = f2b((v1 * rn + qe[h * 64 + d0 + 1]) * sp);
    o.z = f2b((v2 * rn + qe[h * 64 + d0 + 2]) * sp);
    o.w = f2b((v3 * rn + qe[h * 64 + d0 + 3]) * sp);
    *(ushort4*)&Q[base] = o;
}

// ---------------------------------------------------------------------------
// Vt[b,h,d,n] = V[b,n,h*64+d]   (64x64 tiles through LDS; bf16 ws)
// ---------------------------------------------------------------------------
__global__ __launch_bounds__(256) void vtrans_kernel(
    const unsigned short* __restrict__ V,
    unsigned short* __restrict__ Vt)
{
    __shared__ __attribute__((aligned(16))) unsigned short tile[64 * 72];
    const int t = threadIdx.x;
    const int n0 = blockIdx.x * 64;
    const int bh = blockIdx.y, b = bh >> 4, h = bh & 15;
#pragma unroll
    for (int p = 0; p < 2; ++p) {
        int c = t + p * 256;
        int row = c >> 3, c8 = (c & 7) << 3;
        *(s16x8*)&tile[row * 72 + c8] =
            *(const s16x8*)&V[(size_t)(b * 2048 + n0 + row) * 1024 + h * 64 + c8];
    }
    __syncthreads();
    const int d = t >> 2, seg = (t & 3) << 4;
    __attribute__((aligned(16))) unsigned short tmp[16];
#pragma unroll
    for (int i = 0; i < 16; ++i) tmp[i] = tile[(seg + i) * 72 + d];
    size_t obase = ((size_t)(b * 16 + h) * 64 + d) * 2048 + n0 + seg;
    *(int4*)&Vt[obase] = *(int4*)&tmp[0];
    *(int4*)&Vt[obase + 8] = *(int4*)&tmp[8];
}

// ---------------------------------------------------------------------------
// Flash attention: 64 q-rows per block for one (b,h); K/V chunks of 64,
// online softmax, P round-trips LDS (C-layout -> A-layout per m120).
// ---------------------------------------------------------------------------
__global__ __launch_bounds__(256) void attn_kernel(
    const unsigned short* __restrict__ Q,   // q_scaled [B*N][C]
    const unsigned short* __restrict__ Kb,  // [B*N][C]
    const unsigned short* __restrict__ Vt,  // [B][H][64][N]
    unsigned short* __restrict__ Hout)      // [B*N][C]
{
    __shared__ __attribute__((aligned(16))) unsigned short Qs[64 * 72];
    __shared__ __attribute__((aligned(16))) unsigned short Ks[64 * 72];
    __shared__ __attribute__((aligned(16))) unsigned short Vs[64 * 72];
    __shared__ __attribute__((aligned(16))) unsigned short Ps[64 * 72];
    const int t = threadIdx.x, wave = t >> 6, lane = t & 63;
    const int lr = lane & 15, lq = lane >> 4;
    const int bh = blockIdx.y, b = bh >> 4, h = bh & 15;
    const int q0 = blockIdx.x * 64;

#pragma unroll
    for (int p = 0; p < 2; ++p) {
        int c = t + p * 256;
        int row = c >> 3, c8 = (c & 7) << 3;
        *(s16x8*)&Qs[row * 72 + c8] =
            *(const s16x8*)&Q[(size_t)(b * 2048 + q0 + row) * 1024 + h * 64 + c8];
    }

    f32x4 accO[4];
#pragma unroll
    for (int j = 0; j < 4; ++j) accO[j] = (f32x4){0.f, 0.f, 0.f, 0.f};
    float m_i[4], l_i[4];
#pragma unroll
    for (int r = 0; r < 4; ++r) { m_i[r] = -1e30f; l_i[r] = 0.f; }

    for (int kc = 0; kc < 2048; kc += 64) {
        __syncthreads();
#pragma unroll
        for (int p = 0; p < 2; ++p) {
            int c = t + p * 256;
            int row = c >> 3, c8 = (c & 7) << 3;
            *(s16x8*)&Ks[row * 72 + c8] =
                *(const s16x8*)&Kb[(size_t)(b * 2048 + kc + row) * 1024 + h * 64 + c8];
            *(s16x8*)&Vs[row * 72 + c8] =
                *(const s16x8*)&Vt[((size_t)(b * 16 + h) * 64 + row) * 2048 + kc + c8];
        }
        __syncthreads();

        // S = Q * K^T (wave's 16 q-rows x 64 keys)
        f32x4 s[4];
#pragma unroll
        for (int j = 0; j < 4; ++j) s[j] = (f32x4){0.f, 0.f, 0.f, 0.f};
#pragma unroll
        for (int kk = 0; kk < 64; kk += 32) {
            s16x8 aq = *(const s16x8*)&Qs[(wave * 16 + lr) * 72 + kk + lq * 8];
#pragma unroll
            for (int j = 0; j < 4; ++j) {
                s16x8 bk = *(const s16x8*)&Ks[(j * 16 + lr) * 72 + kk + lq * 8];
                s[j] = __builtin_amdgcn_mfma_f32_16x16x32_bf16(aq, bk, s[j], 0, 0, 0);
            }
        }

        // Online softmax per row r (lane holds rows lq*4+r, cols j*16+lr)
#pragma unroll
        for (int r = 0; r < 4; ++r) {
            float sv[4];
            float mx = -1e30f;
#pragma unroll
            for (int j = 0; j < 4; ++j) { sv[j] = s[j][r] * 0.125f; mx = fmaxf(mx, sv[j]); }
            mx = fmaxf(mx, __shfl_xor(mx, 1));
            mx = fmaxf(mx, __shfl_xor(mx, 2));
            mx = fmaxf(mx, __shfl_xor(mx, 4));
            mx = fmaxf(mx, __shfl_xor(mx, 8));
            float mnew = fmaxf(m_i[r], mx);
            float alpha = __expf(m_i[r] - mnew);
            m_i[r] = mnew;
            float rs = 0.f;
#pragma unroll
            for (int j = 0; j < 4; ++j) {
                float p = __expf(sv[j] - mnew);
                rs += p;
                Ps[(wave * 16 + lq * 4 + r) * 72 + j * 16 + lr] = f2b(p);
            }
            rs += __shfl_xor(rs, 1); rs += __shfl_xor(rs, 2);
            rs += __shfl_xor(rs, 4); rs += __shfl_xor(rs, 8);
            l_i[r] = l_i[r] * alpha + rs;
#pragma unroll
            for (int j = 0; j < 4; ++j) accO[j][r] *= alpha;
        }
        __syncthreads();

        // O += P * V   (A = Ps rows [own wave], B = Vs rows = hd index)
#pragma unroll
        for (int kk = 0; kk < 64; kk += 32) {
            s16x8 ap = *(const s16x8*)&Ps[(wave * 16 + lr) * 72 + kk + lq * 8];
#pragma unroll
            for (int j = 0; j < 4; ++j) {
                s16x8 bv = *(const s16x8*)&Vs[(j * 16 + lr) * 72 + kk + lq * 8];
                accO[j] = __builtin_amdgcn_mfma_f32_16x16x32_bf16(ap, bv, accO[j], 0, 0, 0);
            }
        }
    }

#pragma unroll
    for (int r = 0; r < 4; ++r) {
        float inv = 1.f / l_i[r];
        int row = q0 + wave * 16 + lq * 4 + r;
#pragma unroll
        for (int j = 0; j < 4; ++j)
            Hout[(size_t)(b * 2048 + row) * 1024 + h * 64 + j * 16 + lr] =
                f2b(accO[j][r] * inv);
    }
}

// ---------------------------------------------------------------------------
// Gating: g = 2*sw0 + 6*sw1*top3sum; h <- h*g  (in place, bf16 ws).
// One token per block. Wr/br/Ws/bs are fp32.
// ---------------------------------------------------------------------------
__global__ __launch_bounds__(256) void gate_kernel(
    unsigned short* __restrict__ Hb,
    const float* __restrict__ Wr,
    const float* __restrict__ br,
    const float* __restrict__ Ws,
    const float* __restrict__ bs)
{
    __shared__ float red[4][17];
    __shared__ float g_sh;
    const int tok = blockIdx.x, t = threadIdx.x;
    const int wave = t >> 6, lane = t & 63;
    const int c0 = t << 2;
    size_t hbase = (size_t)tok * 1024 + c0;
    ushort4 hr = *(const ushort4*)&Hb[hbase];
    float h0 = b2f(hr.x), h1 = b2f(hr.y), h2 = b2f(hr.z), h3 = b2f(hr.w);

    float acc[17];
#pragma unroll
    for (int j = 0; j < 17; ++j) {
        const float* w = (j < 15) ? &Wr[j * 1024 + c0] : &Ws[(j - 15) * 1024 + c0];
        float4 w4 = *(const float4*)w;
        acc[j] = h0 * w4.x + h1 * w4.y + h2 * w4.z + h3 * w4.w;
    }
#pragma unroll
    for (int j = 0; j < 17; ++j) {
        acc[j] += __shfl_xor(acc[j], 1);
        acc[j] += __shfl_xor(acc[j], 2);
        acc[j] += __shfl_xor(acc[j], 4);
        acc[j] += __shfl_xor(acc[j], 8);
        acc[j] += __shfl_xor(acc[j], 16);
        acc[j] += __shfl_xor(acc[j], 32);
    }
    if (lane == 0) {
#pragma unroll
        for (int j = 0; j < 17; ++j) red[wave][j] = acc[j];
    }
    __syncthreads();
    if (t == 0) {
        float lg[17];
#pragma unroll
        for (int j = 0; j < 17; ++j) {
            float bj = (j < 15) ? br[j] : bs[j - 15];
            lg[j] = red[0][j] + red[1][j] + red[2][j] + red[3][j] + bj;
        }
        float mx = lg[0];
#pragma unroll
        for (int j = 1; j < 15; ++j) mx = fmaxf(mx, lg[j]);
        float sum = 0.f, v1 = -1.f, v2 = -1.f, v3 = -1.f;
#pragma unroll
        for (int j = 0; j < 15; ++j) {
            float e = __expf(lg[j] - mx);
            sum += e;
            if (e > v1)      { v3 = v2; v2 = v1; v1 = e; }
            else if (e > v2) { v3 = v2; v2 = e; }
            else if (e > v3) { v3 = e; }
        }
        float tops = (v1 + v2 + v3) / sum;
        float s0 = lg[15], s1 = lg[16];
        float sm = fmaxf(s0, s1);
        float e0 = __expf(s0 - sm), e1 = __expf(s1 - sm);
        float inv = 1.f / (e0 + e1);
        g_sh = 2.f * (e0 * inv) + 6.f * (e1 * inv) * tops;
    }
    __syncthreads();
    float g = g_sh;
    ushort4 o;
    o.x = f2b(h0 * g); o.y = f2b(h1 * g); o.z = f2b(h2 * g); o.w = f2b(h3 * g);
    *(ushort4*)&Hb[hbase] = o;
}

// ---------------------------------------------------------------------------
extern "C" void kernel_launch(void* const* d_in, const int* in_sizes, int n_in,
                              void* d_out, int out_size, void* d_ws, size_t ws_size,
                              hipStream_t stream)
{
    (void)in_sizes; (void)n_in; (void)out_size; (void)ws_size;
    const float* x   = (const float*)d_in[0];
    const float* Wq  = (const float*)d_in[1];
    const float* bq  = (const float*)d_in[2];
    const float* Wk  = (const float*)d_in[3];
    const float* bk  = (const float*)d_in[4];
    const float* Wv  = (const float*)d_in[5];
    const float* bv  = (const float*)d_in[6];
    const float* Wp  = (const float*)d_in[7];
    const float* bp  = (const float*)d_in[8];
    const float* Wr  = (const float*)d_in[9];
    const float* br  = (const float*)d_in[10];
    const float* Ws  = (const float*)d_in[11];
    const float* bs  = (const float*)d_in[12];
    const float* temperature = (const float*)d_in[13];
    const float* qe  = (const float*)d_in[14];
    float* out = (float*)d_out;

    const size_t NT = 4096ull * 1024ull;
    unsigned short* qb = (unsigned short*)d_ws;
    unsigned short* kb = qb + NT;
    unsigned short* hb = kb + NT;   // holds V, then attention output h, then h*g
    unsigned short* vt = hb + NT;

    dim3 blk(256);
    dim3 gg(32, 8);
    gemm_bias_nt<float, float, unsigned short><<<gg, blk, 0, stream>>>(x, Wq, bq, qb, 4096, 1024, 1024);
    gemm_bias_nt<float, float, unsigned short><<<gg, blk, 0, stream>>>(x, Wk, bk, kb, 4096, 1024, 1024);
    gemm_bias_nt<float, float, unsigned short><<<gg, blk, 0, stream>>>(x, Wv, bv, hb, 4096, 1024, 1024);
    qscale_kernel<<<dim3(4096), blk, 0, stream>>>(qb, temperature, qe);
    vtrans_kernel<<<dim3(32, 32), blk, 0, stream>>>(hb, vt);
    attn_kernel<<<dim3(32, 32), blk, 0, stream>>>(qb, kb, vt, hb);
    gate_kernel<<<dim3(4096), blk, 0, stream>>>(hb, Wr, br, Ws, bs);
    gemm_bias_nt<unsigned short, float, float><<<gg, blk, 0, stream>>>(hb, Wp, bp, out, 4096, 1024, 1024);
}

// Round 3
// 317.387 us; speedup vs baseline: 1.4416x; 1.4416x over previous
//
#include <hip/hip_runtime.h>

typedef short s16x8 __attribute__((ext_vector_type(8)));
typedef float f32x4 __attribute__((ext_vector_type(4)));

__device__ __forceinline__ float b2f(unsigned short u) {
    union { unsigned int i; float f; } v;
    v.i = ((unsigned int)u) << 16;
    return v.f;
}
__device__ __forceinline__ unsigned short f2b(float f) {
    unsigned int x = __builtin_bit_cast(unsigned int, f);
    unsigned int r = (x + 0x7fffu + ((x >> 16) & 1u)) >> 16;
    return (unsigned short)r;
}
__device__ __forceinline__ float fast_exp2(float x) {
#if __has_builtin(__builtin_amdgcn_exp2f)
    return __builtin_amdgcn_exp2f(x);
#else
    return exp2f(x);
#endif
}

// async global->LDS, 16B per lane; LDS dest = base + lane*16 (wave-uniform base)
__device__ __forceinline__ void gl_lds16(const unsigned short* g, unsigned short* l) {
    __builtin_amdgcn_global_load_lds(
        (const __attribute__((address_space(1))) void*)g,
        (__attribute__((address_space(3))) void*)l, 16, 0, 0);
}

__device__ __forceinline__ void store_c(unsigned short* C, size_t idx, float v) { C[idx] = f2b(v); }
__device__ __forceinline__ void store_c(float* C, size_t idx, float v) { C[idx] = v; }

// ---------------------------------------------------------------------------
// fp32 -> bf16 elementwise convert (8 elems/thread)
// ---------------------------------------------------------------------------
__global__ __launch_bounds__(256) void cvt_kernel(
    const float* __restrict__ src, unsigned short* __restrict__ dst, int n8)
{
    int i = blockIdx.x * 256 + threadIdx.x;
    if (i >= n8) return;
    const float* p = src + (size_t)i * 8;
    float4 a = *(const float4*)p;
    float4 b = *(const float4*)(p + 4);
    s16x8 r;
    r[0] = (short)f2b(a.x); r[1] = (short)f2b(a.y);
    r[2] = (short)f2b(a.z); r[3] = (short)f2b(a.w);
    r[4] = (short)f2b(b.x); r[5] = (short)f2b(b.y);
    r[6] = (short)f2b(b.z); r[7] = (short)f2b(b.w);
    *(s16x8*)&dst[(size_t)i * 8] = r;
}

// pack bq|bk|bv -> bqkv[3072] (fp32)
__global__ __launch_bounds__(256) void pack_bias(
    const float* __restrict__ a, const float* __restrict__ b,
    const float* __restrict__ c, float* __restrict__ dst)
{
    int i = blockIdx.x * 256 + threadIdx.x;  // 0..3071
    dst[i] = (i < 1024) ? a[i] : (i < 2048) ? b[i - 1024] : c[i - 2048];
}

// ---------------------------------------------------------------------------
// NT GEMM (m97 structure): C = A[4096][1024] * B[N][1024]^T + bias.
// bf16 in, 128x128 tile, BK=64, unpadded LDS + global_load_lds width 16.
// Column block n0 routed to C0/C1/C2 by n0>>10 (fused QKV; pass same ptr x3
// for a plain single-output GEMM).
// ---------------------------------------------------------------------------
template <typename TC>
__global__ __launch_bounds__(256) void gemm_nt_async(
    const unsigned short* __restrict__ A,
    const unsigned short* __restrict__ Bw,
    const float* __restrict__ bias,
    TC* __restrict__ C0, TC* __restrict__ C1, TC* __restrict__ C2)
{
    __shared__ __attribute__((aligned(16))) unsigned short As[128 * 64];
    __shared__ __attribute__((aligned(16))) unsigned short Bs[128 * 64];
    const int t = threadIdx.x;
    const int wave = t >> 6, lane = t & 63;
    const int m0 = blockIdx.x * 128, n0 = blockIdx.y * 128;
    const int wm = (wave >> 1) * 64, wn = (wave & 1) * 64;
    const int lr = lane & 15, lq = lane >> 4;
    const int srow = lane >> 3, scol = (lane & 7) << 3;  // staging: 8 rows x 64 cols per instr

    f32x4 acc[4][4];
#pragma unroll
    for (int i = 0; i < 4; ++i)
#pragma unroll
        for (int j = 0; j < 4; ++j) acc[i][j] = (f32x4){0.f, 0.f, 0.f, 0.f};

    for (int k0 = 0; k0 < 1024; k0 += 64) {
        __syncthreads();
#pragma unroll
        for (int i = 0; i < 4; ++i) {
            int rb = wave * 32 + i * 8;
            gl_lds16(&A[(size_t)(m0 + rb + srow) * 1024 + k0 + scol], &As[rb * 64]);
            gl_lds16(&Bw[(size_t)(n0 + rb + srow) * 1024 + k0 + scol], &Bs[rb * 64]);
        }
        __syncthreads();
#pragma unroll
        for (int kk = 0; kk < 64; kk += 32) {
            s16x8 af[4], bf[4];
#pragma unroll
            for (int i = 0; i < 4; ++i)
                af[i] = *(const s16x8*)&As[(wm + i * 16 + lr) * 64 + kk + lq * 8];
#pragma unroll
            for (int j = 0; j < 4; ++j)
                bf[j] = *(const s16x8*)&Bs[(wn + j * 16 + lr) * 64 + kk + lq * 8];
#pragma unroll
            for (int i = 0; i < 4; ++i)
#pragma unroll
                for (int j = 0; j < 4; ++j)
                    acc[i][j] = __builtin_amdgcn_mfma_f32_16x16x32_bf16(af[i], bf[j], acc[i][j], 0, 0, 0);
        }
    }
    TC* Cm = (n0 < 1024) ? C0 : (n0 < 2048) ? C1 : C2;
    const int nc = n0 & 1023;
#pragma unroll
    for (int j = 0; j < 4; ++j) {
        int cl = wn + j * 16 + lr;
        float bv = bias[n0 + cl];
#pragma unroll
        for (int i = 0; i < 4; ++i) {
            int rowb = wm + i * 16 + lq * 4;
#pragma unroll
            for (int r = 0; r < 4; ++r)
                store_c(Cm, (size_t)(m0 + rowb + r) * 1024 + nc + cl, acc[i][j][r] + bv);
        }
    }
}

// ---------------------------------------------------------------------------
// q_scaled = (q/||q|| + qe[h]) * softplus(temp[h]) * 1/(8 ln2)   [exp2 fold]
// ---------------------------------------------------------------------------
__global__ __launch_bounds__(256) void qscale_kernel(
    unsigned short* __restrict__ Q,
    const float* __restrict__ temp,
    const float* __restrict__ qe)
{
    const int tok = blockIdx.x, t = threadIdx.x;
    const int h = t >> 4;
    const int c0 = t << 2;
    size_t base = (size_t)tok * 1024 + c0;
    ushort4 raw = *(const ushort4*)&Q[base];
    float v0 = b2f(raw.x), v1 = b2f(raw.y), v2 = b2f(raw.z), v3 = b2f(raw.w);
    float ss = v0 * v0 + v1 * v1 + v2 * v2 + v3 * v3;
    ss += __shfl_xor(ss, 1); ss += __shfl_xor(ss, 2);
    ss += __shfl_xor(ss, 4); ss += __shfl_xor(ss, 8);
    float rn = rsqrtf(ss);
    float tv = temp[h];
    float sp = ((tv > 20.f) ? tv : log1pf(__expf(tv))) * 0.18033688f;  // /(8 ln2)
    int d0 = c0 & 63;
    ushort4 o;
    o.x = f2b((v0 * rn + qe[h * 64 + d0 + 0]) * sp);
    o.y = f2b((v1 * rn + qe[h * 64 + d0 + 1]) * sp);
    o.z = f2b((v2 * rn + qe[h * 64 + d0 + 2]) * sp);
    o.w = f2b((v3 * rn + qe[h * 64 + d0 + 3]) * sp);
    *(ushort4*)&Q[base] = o;
}

// ---------------------------------------------------------------------------
// Vt[b,h,d,n] = V[b,n,h*64+d]
// ---------------------------------------------------------------------------
__global__ __launch_bounds__(256) void vtrans_kernel(
    const unsigned short* __restrict__ V,
    unsigned short* __restrict__ Vt)
{
    __shared__ __attribute__((aligned(16))) unsigned short tile[64 * 72];
    const int t = threadIdx.x;
    const int n0 = blockIdx.x * 64;
    const int bh = blockIdx.y, b = bh >> 4, h = bh & 15;
#pragma unroll
    for (int p = 0; p < 2; ++p) {
        int c = t + p * 256;
        int row = c >> 3, c8 = (c & 7) << 3;
        *(s16x8*)&tile[row * 72 + c8] =
            *(const s16x8*)&V[(size_t)(b * 2048 + n0 + row) * 1024 + h * 64 + c8];
    }
    __syncthreads();
    const int d = t >> 2, seg = (t & 3) << 4;
    __attribute__((aligned(16))) unsigned short tmp[16];
#pragma unroll
    for (int i = 0; i < 16; ++i) tmp[i] = tile[(seg + i) * 72 + d];
    size_t obase = ((size_t)(b * 16 + h) * 64 + d) * 2048 + n0 + seg;
    *(int4*)&Vt[obase] = *(int4*)&tmp[0];
    *(int4*)&Vt[obase + 8] = *(int4*)&tmp[8];
}

// ---------------------------------------------------------------------------
// Flash attention, m=0 softmax (logits bounded), deferred l-reduce.
// 64 q-rows/block for one (b,h); async K/V staging; Ps wave-private.
// ---------------------------------------------------------------------------
__global__ __launch_bounds__(256) void attn_kernel(
    const unsigned short* __restrict__ Q,   // q_scaled [B*N][C] (exp2-folded)
    const unsigned short* __restrict__ Kb,  // [B*N][C]
    const unsigned short* __restrict__ Vt,  // [B][H][64][N]
    unsigned short* __restrict__ Hout)      // [B*N][C]
{
    __shared__ __attribute__((aligned(16))) unsigned short Qs[64 * 64];
    __shared__ __attribute__((aligned(16))) unsigned short Ks[64 * 64];
    __shared__ __attribute__((aligned(16))) unsigned short Vs[64 * 64];
    __shared__ __attribute__((aligned(16))) unsigned short Ps[64 * 72];
    const int t = threadIdx.x, wave = t >> 6, lane = t & 63;
    const int lr = lane & 15, lq = lane >> 4;
    const int bh = blockIdx.y, b = bh >> 4, h = bh & 15;
    const int q0 = blockIdx.x * 64;
    const int srow = lane >> 3, scol = (lane & 7) << 3;

#pragma unroll
    for (int p = 0; p < 2; ++p) {
        int c = t + p * 256;
        int row = c >> 3, c8 = (c & 7) << 3;
        *(s16x8*)&Qs[row * 64 + c8] =
            *(const s16x8*)&Q[(size_t)(b * 2048 + q0 + row) * 1024 + h * 64 + c8];
    }

    f32x4 accO[4];
#pragma unroll
    for (int j = 0; j < 4; ++j) accO[j] = (f32x4){0.f, 0.f, 0.f, 0.f};
    float lsum[4] = {0.f, 0.f, 0.f, 0.f};

    for (int kc = 0; kc < 2048; kc += 64) {
        __syncthreads();
#pragma unroll
        for (int i = 0; i < 2; ++i) {
            int rb = wave * 16 + i * 8;
            gl_lds16(&Kb[(size_t)(b * 2048 + kc + rb + srow) * 1024 + h * 64 + scol], &Ks[rb * 64]);
            gl_lds16(&Vt[((size_t)(b * 16 + h) * 64 + rb + srow) * 2048 + kc + scol], &Vs[rb * 64]);
        }
        __syncthreads();

        // S = Q * K^T (wave's 16 q-rows x 64 keys); logits pre-scaled for exp2
        f32x4 s[4];
#pragma unroll
        for (int j = 0; j < 4; ++j) s[j] = (f32x4){0.f, 0.f, 0.f, 0.f};
#pragma unroll
        for (int kk = 0; kk < 64; kk += 32) {
            s16x8 aq = *(const s16x8*)&Qs[(wave * 16 + lr) * 64 + kk + lq * 8];
#pragma unroll
            for (int j = 0; j < 4; ++j) {
                s16x8 bk = *(const s16x8*)&Ks[(j * 16 + lr) * 64 + kk + lq * 8];
                s[j] = __builtin_amdgcn_mfma_f32_16x16x32_bf16(aq, bk, s[j], 0, 0, 0);
            }
        }

        // p = 2^s  (no max subtraction: |s| <= ~6, safe); accumulate row sums
#pragma unroll
        for (int r = 0; r < 4; ++r) {
            float ps = 0.f;
#pragma unroll
            for (int j = 0; j < 4; ++j) {
                float p = fast_exp2(s[j][r]);
                ps += p;
                Ps[(wave * 16 + lq * 4 + r) * 72 + j * 16 + lr] = f2b(p);
            }
            lsum[r] += ps;
        }
        // no barrier: Ps rows are wave-private

        // O += P * V
#pragma unroll
        for (int kk = 0; kk < 64; kk += 32) {
            s16x8 ap = *(const s16x8*)&Ps[(wave * 16 + lr) * 72 + kk + lq * 8];
#pragma unroll
            for (int j = 0; j < 4; ++j) {
                s16x8 bv = *(const s16x8*)&Vs[(j * 16 + lr) * 64 + kk + lq * 8];
                accO[j] = __builtin_amdgcn_mfma_f32_16x16x32_bf16(ap, bv, accO[j], 0, 0, 0);
            }
        }
    }

#pragma unroll
    for (int r = 0; r < 4; ++r) {
        float l = lsum[r];
        l += __shfl_xor(l, 1); l += __shfl_xor(l, 2);
        l += __shfl_xor(l, 4); l += __shfl_xor(l, 8);
        float inv = 1.f / l;
        int row = q0 + wave * 16 + lq * 4 + r;
#pragma unroll
        for (int j = 0; j < 4; ++j)
            Hout[(size_t)(b * 2048 + row) * 1024 + h * 64 + j * 16 + lr] =
                f2b(accO[j][r] * inv);
    }
}

// ---------------------------------------------------------------------------
// Gating: g = 2*sw0 + 6*sw1*top3sum; h <- h*g (in place, bf16).
// ---------------------------------------------------------------------------
__global__ __launch_bounds__(256) void gate_kernel(
    unsigned short* __restrict__ Hb,
    const float* __restrict__ Wr,
    const float* __restrict__ br,
    const float* __restrict__ Ws,
    const float* __restrict__ bs)
{
    __shared__ float red[4][17];
    __shared__ float g_sh;
    const int tok = blockIdx.x, t = threadIdx.x;
    const int wave = t >> 6, lane = t & 63;
    const int c0 = t << 2;
    size_t hbase = (size_t)tok * 1024 + c0;
    ushort4 hr = *(const ushort4*)&Hb[hbase];
    float h0 = b2f(hr.x), h1 = b2f(hr.y), h2 = b2f(hr.z), h3 = b2f(hr.w);

    float acc[17];
#pragma unroll
    for (int j = 0; j < 17; ++j) {
        const float* w = (j < 15) ? &Wr[j * 1024 + c0] : &Ws[(j - 15) * 1024 + c0];
        float4 w4 = *(const float4*)w;
        acc[j] = h0 * w4.x + h1 * w4.y + h2 * w4.z + h3 * w4.w;
    }
#pragma unroll
    for (int j = 0; j < 17; ++j) {
        acc[j] += __shfl_xor(acc[j], 1);
        acc[j] += __shfl_xor(acc[j], 2);
        acc[j] += __shfl_xor(acc[j], 4);
        acc[j] += __shfl_xor(acc[j], 8);
        acc[j] += __shfl_xor(acc[j], 16);
        acc[j] += __shfl_xor(acc[j], 32);
    }
    if (lane == 0) {
#pragma unroll
        for (int j = 0; j < 17; ++j) red[wave][j] = acc[j];
    }
    __syncthreads();
    if (t == 0) {
        float lg[17];
#pragma unroll
        for (int j = 0; j < 17; ++j) {
            float bj = (j < 15) ? br[j] : bs[j - 15];
            lg[j] = red[0][j] + red[1][j] + red[2][j] + red[3][j] + bj;
        }
        float mx = lg[0];
#pragma unroll
        for (int j = 1; j < 15; ++j) mx = fmaxf(mx, lg[j]);
        float sum = 0.f, v1 = -1.f, v2 = -1.f, v3 = -1.f;
#pragma unroll
        for (int j = 0; j < 15; ++j) {
            float e = __expf(lg[j] - mx);
            sum += e;
            if (e > v1)      { v3 = v2; v2 = v1; v1 = e; }
            else if (e > v2) { v3 = v2; v2 = e; }
            else if (e > v3) { v3 = e; }
        }
        float tops = (v1 + v2 + v3) / sum;
        float s0 = lg[15], s1 = lg[16];
        float sm = fmaxf(s0, s1);
        float e0 = __expf(s0 - sm), e1 = __expf(s1 - sm);
        float inv = 1.f / (e0 + e1);
        g_sh = 2.f * (e0 * inv) + 6.f * (e1 * inv) * tops;
    }
    __syncthreads();
    float g = g_sh;
    ushort4 o;
    o.x = f2b(h0 * g); o.y = f2b(h1 * g); o.z = f2b(h2 * g); o.w = f2b(h3 * g);
    *(ushort4*)&Hb[hbase] = o;
}

// ---------------------------------------------------------------------------
extern "C" void kernel_launch(void* const* d_in, const int* in_sizes, int n_in,
                              void* d_out, int out_size, void* d_ws, size_t ws_size,
                              hipStream_t stream)
{
    (void)in_sizes; (void)n_in; (void)out_size; (void)ws_size;
    const float* x   = (const float*)d_in[0];
    const float* Wq  = (const float*)d_in[1];
    const float* bq  = (const float*)d_in[2];
    const float* Wk  = (const float*)d_in[3];
    const float* bk  = (const float*)d_in[4];
    const float* Wv  = (const float*)d_in[5];
    const float* bv  = (const float*)d_in[6];
    const float* Wp  = (const float*)d_in[7];
    const float* bp  = (const float*)d_in[8];
    const float* Wr  = (const float*)d_in[9];
    const float* br  = (const float*)d_in[10];
    const float* Ws  = (const float*)d_in[11];
    const float* bs  = (const float*)d_in[12];
    const float* temperature = (const float*)d_in[13];
    const float* qe  = (const float*)d_in[14];
    float* out = (float*)d_out;

    const size_t MB = 1048576;
    // ws (proven >= 32 MiB): qb | kb | vb | wqkv(->wpb) | bqkv
    unsigned short* qb   = (unsigned short*)d_ws;                       // 8 MiB
    unsigned short* kb   = (unsigned short*)((char*)d_ws + 8 * MB);     // 8 MiB
    unsigned short* vb   = (unsigned short*)((char*)d_ws + 16 * MB);    // 8 MiB (V -> h -> h*g)
    unsigned short* wqkv = (unsigned short*)((char*)d_ws + 24 * MB);    // 6 MiB (then wpb 2 MiB)
    unsigned short* wpb  = wqkv;                                        // reuse after QKV GEMM
    float*          bqkv = (float*)((char*)d_ws + 30 * MB);             // 12 KiB
    // d_out (16 MiB fp32) doubles as scratch until the final GEMM:
    unsigned short* xb = (unsigned short*)d_out;                        // 8 MiB bf16 x
    unsigned short* vt = xb + 4 * MB;                                   // 8 MiB V^T

    dim3 blk(256);
    cvt_kernel<<<dim3(2048), blk, 0, stream>>>(x, xb, 524288);
    cvt_kernel<<<dim3(512),  blk, 0, stream>>>(Wq, wqkv,            131072);
    cvt_kernel<<<dim3(512),  blk, 0, stream>>>(Wk, wqkv + 1048576,  131072);
    cvt_kernel<<<dim3(512),  blk, 0, stream>>>(Wv, wqkv + 2097152,  131072);
    pack_bias<<<dim3(12), blk, 0, stream>>>(bq, bk, bv, bqkv);
    gemm_nt_async<unsigned short><<<dim3(32, 24), blk, 0, stream>>>(xb, wqkv, bqkv, qb, kb, vb);
    cvt_kernel<<<dim3(512), blk, 0, stream>>>(Wp, wpb, 131072);   // after QKV GEMM (region reuse)
    qscale_kernel<<<dim3(4096), blk, 0, stream>>>(qb, temperature, qe);
    vtrans_kernel<<<dim3(32, 32), blk, 0, stream>>>(vb, vt);
    attn_kernel<<<dim3(32, 32), blk, 0, stream>>>(qb, kb, vt, vb);
    gate_kernel<<<dim3(4096), blk, 0, stream>>>(vb, Wr, br, Ws, bs);
    gemm_nt_async<float><<<dim3(32, 8), blk, 0, stream>>>(vb, wpb, bp, out, out, out);
}

// Round 4
// 274.589 us; speedup vs baseline: 1.6663x; 1.1559x over previous
//
#include <hip/hip_runtime.h>

typedef short s16x8 __attribute__((ext_vector_type(8)));
typedef float f32x4 __attribute__((ext_vector_type(4)));

__device__ __forceinline__ float b2f(unsigned short u) {
    union { unsigned int i; float f; } v;
    v.i = ((unsigned int)u) << 16;
    return v.f;
}
__device__ __forceinline__ unsigned short f2b(float f) {
    unsigned int x = __builtin_bit_cast(unsigned int, f);
    unsigned int r = (x + 0x7fffu + ((x >> 16) & 1u)) >> 16;
    return (unsigned short)r;
}
__device__ __forceinline__ float fast_exp2(float x) {
#if __has_builtin(__builtin_amdgcn_exp2f)
    return __builtin_amdgcn_exp2f(x);
#else
    return exp2f(x);
#endif
}

// async global->LDS, 16B per lane; LDS dest = base + lane*16 (wave-uniform base)
__device__ __forceinline__ void gl_lds16(const unsigned short* g, unsigned short* l) {
    __builtin_amdgcn_global_load_lds(
        (const __attribute__((address_space(1))) void*)g,
        (__attribute__((address_space(3))) void*)l, 16, 0, 0);
}

__device__ __forceinline__ void store_c(unsigned short* C, size_t idx, float v) { C[idx] = f2b(v); }
__device__ __forceinline__ void store_c(float* C, size_t idx, float v) { C[idx] = v; }

// XOR-swizzle: 16B block c of row r lives at physical block c^(r%8).
// Kills the row-stride-128B bank aliasing while staying global_load_lds-able.

// ---------------------------------------------------------------------------
// fp32 -> bf16 elementwise convert (8 elems/thread)
// ---------------------------------------------------------------------------
__global__ __launch_bounds__(256) void cvt_kernel(
    const float* __restrict__ src, unsigned short* __restrict__ dst, int n8)
{
    int i = blockIdx.x * 256 + threadIdx.x;
    if (i >= n8) return;
    const float* p = src + (size_t)i * 8;
    float4 a = *(const float4*)p;
    float4 b = *(const float4*)(p + 4);
    s16x8 r;
    r[0] = (short)f2b(a.x); r[1] = (short)f2b(a.y);
    r[2] = (short)f2b(a.z); r[3] = (short)f2b(a.w);
    r[4] = (short)f2b(b.x); r[5] = (short)f2b(b.y);
    r[6] = (short)f2b(b.z); r[7] = (short)f2b(b.w);
    *(s16x8*)&dst[(size_t)i * 8] = r;
}

// pack bq|bk|bv -> bqkv[3072] (fp32)
__global__ __launch_bounds__(256) void pack_bias(
    const float* __restrict__ a, const float* __restrict__ b,
    const float* __restrict__ c, float* __restrict__ dst)
{
    int i = blockIdx.x * 256 + threadIdx.x;  // 0..3071
    dst[i] = (i < 1024) ? a[i] : (i < 2048) ? b[i - 1024] : c[i - 2048];
}

// ---------------------------------------------------------------------------
// NT GEMM (m97 + swizzle): C = A[4096][1024] * B[N][1024]^T + bias.
// bf16 in, 128x128 tile, BK=64, XOR-swizzled LDS + global_load_lds width 16.
// ---------------------------------------------------------------------------
template <typename TC>
__global__ __launch_bounds__(256) void gemm_nt_async(
    const unsigned short* __restrict__ A,
    const unsigned short* __restrict__ Bw,
    const float* __restrict__ bias,
    TC* __restrict__ C0, TC* __restrict__ C1, TC* __restrict__ C2)
{
    __shared__ __attribute__((aligned(16))) unsigned short As[128 * 64];
    __shared__ __attribute__((aligned(16))) unsigned short Bs[128 * 64];
    const int t = threadIdx.x;
    const int wave = t >> 6, lane = t & 63;
    const int m0 = blockIdx.x * 128, n0 = blockIdx.y * 128;
    const int wm = (wave >> 1) * 64, wn = (wave & 1) * 64;
    const int lr = lane & 15, lq = lane >> 4;
    const int srow = lane >> 3;                       // 0..7 within 8-row group
    const int scol = (((lane & 7) ^ srow) << 3);      // swizzled SOURCE column

    f32x4 acc[4][4];
#pragma unroll
    for (int i = 0; i < 4; ++i)
#pragma unroll
        for (int j = 0; j < 4; ++j) acc[i][j] = (f32x4){0.f, 0.f, 0.f, 0.f};

    for (int k0 = 0; k0 < 1024; k0 += 64) {
        __syncthreads();
#pragma unroll
        for (int i = 0; i < 4; ++i) {
            int rb = wave * 32 + i * 8;
            gl_lds16(&A[(size_t)(m0 + rb + srow) * 1024 + k0 + scol], &As[rb * 64]);
            gl_lds16(&Bw[(size_t)(n0 + rb + srow) * 1024 + k0 + scol], &Bs[rb * 64]);
        }
        __syncthreads();
#pragma unroll
        for (int kk = 0; kk < 64; kk += 32) {
            const int gb = (kk >> 3) + lq;            // logical 16B block
            const int po = ((gb ^ (lr & 7)) << 3);    // physical elem offset
            s16x8 af[4], bf[4];
#pragma unroll
            for (int i = 0; i < 4; ++i)
                af[i] = *(const s16x8*)&As[(wm + i * 16 + lr) * 64 + po];
#pragma unroll
            for (int j = 0; j < 4; ++j)
                bf[j] = *(const s16x8*)&Bs[(wn + j * 16 + lr) * 64 + po];
#pragma unroll
            for (int i = 0; i < 4; ++i)
#pragma unroll
                for (int j = 0; j < 4; ++j)
                    acc[i][j] = __builtin_amdgcn_mfma_f32_16x16x32_bf16(af[i], bf[j], acc[i][j], 0, 0, 0);
        }
    }
    TC* Cm = (n0 < 1024) ? C0 : (n0 < 2048) ? C1 : C2;
    const int nc = n0 & 1023;
#pragma unroll
    for (int j = 0; j < 4; ++j) {
        int cl = wn + j * 16 + lr;
        float bv = bias[n0 + cl];
#pragma unroll
        for (int i = 0; i < 4; ++i) {
            int rowb = wm + i * 16 + lq * 4;
#pragma unroll
            for (int r = 0; r < 4; ++r)
                store_c(Cm, (size_t)(m0 + rowb + r) * 1024 + nc + cl, acc[i][j][r] + bv);
        }
    }
}

// ---------------------------------------------------------------------------
// q_scaled = (q/||q|| + qe[h]) * softplus(temp[h]) * 1/(8 ln2)   [exp2 fold]
// ---------------------------------------------------------------------------
__global__ __launch_bounds__(256) void qscale_kernel(
    unsigned short* __restrict__ Q,
    const float* __restrict__ temp,
    const float* __restrict__ qe)
{
    const int tok = blockIdx.x, t = threadIdx.x;
    const int h = t >> 4;
    const int c0 = t << 2;
    size_t base = (size_t)tok * 1024 + c0;
    ushort4 raw = *(const ushort4*)&Q[base];
    float v0 = b2f(raw.x), v1 = b2f(raw.y), v2 = b2f(raw.z), v3 = b2f(raw.w);
    float ss = v0 * v0 + v1 * v1 + v2 * v2 + v3 * v3;
    ss += __shfl_xor(ss, 1); ss += __shfl_xor(ss, 2);
    ss += __shfl_xor(ss, 4); ss += __shfl_xor(ss, 8);
    float rn = rsqrtf(ss);
    float tv = temp[h];
    float sp = ((tv > 20.f) ? tv : log1pf(__expf(tv))) * 0.18033688f;  // /(8 ln2)
    int d0 = c0 & 63;
    ushort4 o;
    o.x = f2b((v0 * rn + qe[h * 64 + d0 + 0]) * sp);
    o.y = f2b((v1 * rn + qe[h * 64 + d0 + 1]) * sp);
    o.z = f2b((v2 * rn + qe[h * 64 + d0 + 2]) * sp);
    o.w = f2b((v3 * rn + qe[h * 64 + d0 + 3]) * sp);
    *(ushort4*)&Q[base] = o;
}

// ---------------------------------------------------------------------------
// Vt[b,h,d,n] = V[b,n,h*64+d]
// ---------------------------------------------------------------------------
__global__ __launch_bounds__(256) void vtrans_kernel(
    const unsigned short* __restrict__ V,
    unsigned short* __restrict__ Vt)
{
    __shared__ __attribute__((aligned(16))) unsigned short tile[64 * 72];
    const int t = threadIdx.x;
    const int n0 = blockIdx.x * 64;
    const int bh = blockIdx.y, b = bh >> 4, h = bh & 15;
#pragma unroll
    for (int p = 0; p < 2; ++p) {
        int c = t + p * 256;
        int row = c >> 3, c8 = (c & 7) << 3;
        *(s16x8*)&tile[row * 72 + c8] =
            *(const s16x8*)&V[(size_t)(b * 2048 + n0 + row) * 1024 + h * 64 + c8];
    }
    __syncthreads();
    const int d = t >> 2, seg = (t & 3) << 4;
    __attribute__((aligned(16))) unsigned short tmp[16];
#pragma unroll
    for (int i = 0; i < 16; ++i) tmp[i] = tile[(seg + i) * 72 + d];
    size_t obase = ((size_t)(b * 16 + h) * 64 + d) * 2048 + n0 + seg;
    *(int4*)&Vt[obase] = *(int4*)&tmp[0];
    *(int4*)&Vt[obase + 8] = *(int4*)&tmp[8];
}

// ---------------------------------------------------------------------------
// Flash attention, m=0 softmax (bounded logits), deferred l-reduce,
// XOR-swizzled Qs/Ks/Vs, Ps (72-stride) wave-private round-trip.
// ---------------------------------------------------------------------------
__global__ __launch_bounds__(256) void attn_kernel(
    const unsigned short* __restrict__ Q,   // q_scaled [B*N][C] (exp2-folded)
    const unsigned short* __restrict__ Kb,  // [B*N][C]
    const unsigned short* __restrict__ Vt,  // [B][H][64][N]
    unsigned short* __restrict__ Hout)      // [B*N][C]
{
    __shared__ __attribute__((aligned(16))) unsigned short Qs[64 * 64];
    __shared__ __attribute__((aligned(16))) unsigned short Ks[64 * 64];
    __shared__ __attribute__((aligned(16))) unsigned short Vs[64 * 64];
    __shared__ __attribute__((aligned(16))) unsigned short Ps[64 * 72];
    const int t = threadIdx.x, wave = t >> 6, lane = t & 63;
    const int lr = lane & 15, lq = lane >> 4;
    const int bh = blockIdx.y, b = bh >> 4, h = bh & 15;
    const int q0 = blockIdx.x * 64;
    const int srow = lane >> 3;
    const int scol = (((lane & 7) ^ srow) << 3);

#pragma unroll
    for (int p = 0; p < 2; ++p) {
        int c = t + p * 256;
        int row = c >> 3, cb = c & 7;
        // LDS[row][cb] = global[row][cb ^ (row%8)]
        *(s16x8*)&Qs[row * 64 + cb * 8] =
            *(const s16x8*)&Q[(size_t)(b * 2048 + q0 + row) * 1024 + h * 64 + ((cb ^ (row & 7)) << 3)];
    }

    f32x4 accO[4];
#pragma unroll
    for (int j = 0; j < 4; ++j) accO[j] = (f32x4){0.f, 0.f, 0.f, 0.f};
    float lsum[4] = {0.f, 0.f, 0.f, 0.f};

    for (int kc = 0; kc < 2048; kc += 64) {
        __syncthreads();
#pragma unroll
        for (int i = 0; i < 2; ++i) {
            int rb = wave * 16 + i * 8;
            gl_lds16(&Kb[(size_t)(b * 2048 + kc + rb + srow) * 1024 + h * 64 + scol], &Ks[rb * 64]);
            gl_lds16(&Vt[((size_t)(b * 16 + h) * 64 + rb + srow) * 2048 + kc + scol], &Vs[rb * 64]);
        }
        __syncthreads();

        // S = Q * K^T (wave's 16 q-rows x 64 keys); logits pre-scaled for exp2
        f32x4 s[4];
#pragma unroll
        for (int j = 0; j < 4; ++j) s[j] = (f32x4){0.f, 0.f, 0.f, 0.f};
#pragma unroll
        for (int kk = 0; kk < 64; kk += 32) {
            const int po = ((((kk >> 3) + lq) ^ (lr & 7)) << 3);
            s16x8 aq = *(const s16x8*)&Qs[(wave * 16 + lr) * 64 + po];
#pragma unroll
            for (int j = 0; j < 4; ++j) {
                s16x8 bk = *(const s16x8*)&Ks[(j * 16 + lr) * 64 + po];
                s[j] = __builtin_amdgcn_mfma_f32_16x16x32_bf16(aq, bk, s[j], 0, 0, 0);
            }
        }

        // p = 2^s  (no max subtraction: |s| bounded); accumulate row sums
#pragma unroll
        for (int r = 0; r < 4; ++r) {
            float ps = 0.f;
#pragma unroll
            for (int j = 0; j < 4; ++j) {
                float p = fast_exp2(s[j][r]);
                ps += p;
                Ps[(wave * 16 + lq * 4 + r) * 72 + j * 16 + lr] = f2b(p);
            }
            lsum[r] += ps;
        }
        // no barrier: Ps rows are wave-private

        // O += P * V
#pragma unroll
        for (int kk = 0; kk < 64; kk += 32) {
            const int po = ((((kk >> 3) + lq) ^ (lr & 7)) << 3);
            s16x8 ap = *(const s16x8*)&Ps[(wave * 16 + lr) * 72 + kk + lq * 8];
#pragma unroll
            for (int j = 0; j < 4; ++j) {
                s16x8 bv = *(const s16x8*)&Vs[(j * 16 + lr) * 64 + po];
                accO[j] = __builtin_amdgcn_mfma_f32_16x16x32_bf16(ap, bv, accO[j], 0, 0, 0);
            }
        }
    }

#pragma unroll
    for (int r = 0; r < 4; ++r) {
        float l = lsum[r];
        l += __shfl_xor(l, 1); l += __shfl_xor(l, 2);
        l += __shfl_xor(l, 4); l += __shfl_xor(l, 8);
        float inv = 1.f / l;
        int row = q0 + wave * 16 + lq * 4 + r;
#pragma unroll
        for (int j = 0; j < 4; ++j)
            Hout[(size_t)(b * 2048 + row) * 1024 + h * 64 + j * 16 + lr] =
                f2b(accO[j][r] * inv);
    }
}

// ---------------------------------------------------------------------------
// Gating: g = 2*sw0 + 6*sw1*top3sum; h <- h*g (in place, bf16).
// ---------------------------------------------------------------------------
__global__ __launch_bounds__(256) void gate_kernel(
    unsigned short* __restrict__ Hb,
    const float* __restrict__ Wr,
    const float* __restrict__ br,
    const float* __restrict__ Ws,
    const float* __restrict__ bs)
{
    __shared__ float red[4][17];
    __shared__ float g_sh;
    const int tok = blockIdx.x, t = threadIdx.x;
    const int wave = t >> 6, lane = t & 63;
    const int c0 = t << 2;
    size_t hbase = (size_t)tok * 1024 + c0;
    ushort4 hr = *(const ushort4*)&Hb[hbase];
    float h0 = b2f(hr.x), h1 = b2f(hr.y), h2 = b2f(hr.z), h3 = b2f(hr.w);

    float acc[17];
#pragma unroll
    for (int j = 0; j < 17; ++j) {
        const float* w = (j < 15) ? &Wr[j * 1024 + c0] : &Ws[(j - 15) * 1024 + c0];
        float4 w4 = *(const float4*)w;
        acc[j] = h0 * w4.x + h1 * w4.y + h2 * w4.z + h3 * w4.w;
    }
#pragma unroll
    for (int j = 0; j < 17; ++j) {
        acc[j] += __shfl_xor(acc[j], 1);
        acc[j] += __shfl_xor(acc[j], 2);
        acc[j] += __shfl_xor(acc[j], 4);
        acc[j] += __shfl_xor(acc[j], 8);
        acc[j] += __shfl_xor(acc[j], 16);
        acc[j] += __shfl_xor(acc[j], 32);
    }
    if (lane == 0) {
#pragma unroll
        for (int j = 0; j < 17; ++j) red[wave][j] = acc[j];
    }
    __syncthreads();
    if (t == 0) {
        float lg[17];
#pragma unroll
        for (int j = 0; j < 17; ++j) {
            float bj = (j < 15) ? br[j] : bs[j - 15];
            lg[j] = red[0][j] + red[1][j] + red[2][j] + red[3][j] + bj;
        }
        float mx = lg[0];
#pragma unroll
        for (int j = 1; j < 15; ++j) mx = fmaxf(mx, lg[j]);
        float sum = 0.f, v1 = -1.f, v2 = -1.f, v3 = -1.f;
#pragma unroll
        for (int j = 0; j < 15; ++j) {
            float e = __expf(lg[j] - mx);
            sum += e;
            if (e > v1)      { v3 = v2; v2 = v1; v1 = e; }
            else if (e > v2) { v3 = v2; v2 = e; }
            else if (e > v3) { v3 = e; }
        }
        float tops = (v1 + v2 + v3) / sum;
        float s0 = lg[15], s1 = lg[16];
        float sm = fmaxf(s0, s1);
        float e0 = __expf(s0 - sm), e1 = __expf(s1 - sm);
        float inv = 1.f / (e0 + e1);
        g_sh = 2.f * (e0 * inv) + 6.f * (e1 * inv) * tops;
    }
    __syncthreads();
    float g = g_sh;
    ushort4 o;
    o.x = f2b(h0 * g); o.y = f2b(h1 * g); o.z = f2b(h2 * g); o.w = f2b(h3 * g);
    *(ushort4*)&Hb[hbase] = o;
}

// ---------------------------------------------------------------------------
extern "C" void kernel_launch(void* const* d_in, const int* in_sizes, int n_in,
                              void* d_out, int out_size, void* d_ws, size_t ws_size,
                              hipStream_t stream)
{
    (void)in_sizes; (void)n_in; (void)out_size; (void)ws_size;
    const float* x   = (const float*)d_in[0];
    const float* Wq  = (const float*)d_in[1];
    const float* bq  = (const float*)d_in[2];
    const float* Wk  = (const float*)d_in[3];
    const float* bk  = (const float*)d_in[4];
    const float* Wv  = (const float*)d_in[5];
    const float* bv  = (const float*)d_in[6];
    const float* Wp  = (const float*)d_in[7];
    const float* bp  = (const float*)d_in[8];
    const float* Wr  = (const float*)d_in[9];
    const float* br  = (const float*)d_in[10];
    const float* Ws  = (const float*)d_in[11];
    const float* bs  = (const float*)d_in[12];
    const float* temperature = (const float*)d_in[13];
    const float* qe  = (const float*)d_in[14];
    float* out = (float*)d_out;

    const size_t MB = 1048576;
    // ws: qb | kb | vb | wqkv(->wpb) | bqkv
    unsigned short* qb   = (unsigned short*)d_ws;                       // 8 MiB
    unsigned short* kb   = (unsigned short*)((char*)d_ws + 8 * MB);     // 8 MiB
    unsigned short* vb   = (unsigned short*)((char*)d_ws + 16 * MB);    // 8 MiB (V -> h -> h*g)
    unsigned short* wqkv = (unsigned short*)((char*)d_ws + 24 * MB);    // 6 MiB (then wpb)
    unsigned short* wpb  = wqkv;                                        // reuse after QKV GEMM
    float*          bqkv = (float*)((char*)d_ws + 30 * MB);             // 12 KiB
    // d_out (16 MiB fp32) doubles as scratch until the final GEMM:
    unsigned short* xb = (unsigned short*)d_out;                        // 8 MiB bf16 x
    unsigned short* vt = xb + 4 * MB;                                   // 8 MiB V^T

    dim3 blk(256);
    cvt_kernel<<<dim3(2048), blk, 0, stream>>>(x, xb, 524288);
    cvt_kernel<<<dim3(512),  blk, 0, stream>>>(Wq, wqkv,            131072);
    cvt_kernel<<<dim3(512),  blk, 0, stream>>>(Wk, wqkv + 1048576,  131072);
    cvt_kernel<<<dim3(512),  blk, 0, stream>>>(Wv, wqkv + 2097152,  131072);
    pack_bias<<<dim3(12), blk, 0, stream>>>(bq, bk, bv, bqkv);
    gemm_nt_async<unsigned short><<<dim3(32, 24), blk, 0, stream>>>(xb, wqkv, bqkv, qb, kb, vb);
    cvt_kernel<<<dim3(512), blk, 0, stream>>>(Wp, wpb, 131072);   // after QKV GEMM (region reuse)
    qscale_kernel<<<dim3(4096), blk, 0, stream>>>(qb, temperature, qe);
    vtrans_kernel<<<dim3(32, 32), blk, 0, stream>>>(vb, vt);
    attn_kernel<<<dim3(32, 32), blk, 0, stream>>>(qb, kb, vt, vb);
    gate_kernel<<<dim3(4096), blk, 0, stream>>>(vb, Wr, br, Ws, bs);
    gemm_nt_async<float><<<dim3(32, 8), blk, 0, stream>>>(vb, wpb, bp, out, out, out);
}

// Round 5
// 256.543 us; speedup vs baseline: 1.7836x; 1.0703x over previous
//
#include <hip/hip_runtime.h>
#include <hip/hip_bf16.h>

typedef short s16x8 __attribute__((ext_vector_type(8)));
typedef float f32x4 __attribute__((ext_vector_type(4)));

__device__ __forceinline__ float b2f(unsigned short u) {
    union { unsigned int i; float f; } v;
    v.i = ((unsigned int)u) << 16;
    return v.f;
}
__device__ __forceinline__ unsigned short f2b(float f) {
    unsigned int x = __builtin_bit_cast(unsigned int, f);
    unsigned int r = (x + 0x7fffu + ((x >> 16) & 1u)) >> 16;
    return (unsigned short)r;
}
// packed fp32x2 -> bf16x2 (v_cvt_pk_bf16_f32 on gfx950); lo = a, hi = b
__device__ __forceinline__ unsigned int pkbf16(float a, float b) {
    union { __hip_bfloat162 h; unsigned int u; } v;
    v.h = __float22bfloat162_rn(make_float2(a, b));
    return v.u;
}
__device__ __forceinline__ float fast_exp2(float x) { return exp2f(x); }

// async global->LDS, 16B/lane; LDS dest = wave-uniform base + lane*16
__device__ __forceinline__ void gl_lds16(const unsigned short* g, unsigned short* l) {
    __builtin_amdgcn_global_load_lds(
        (const __attribute__((address_space(1))) void*)g,
        (__attribute__((address_space(3))) void*)l, 16, 0, 0);
}

// XOR-swizzle: 16B block c of row r lives at physical block c^(r%8).

// ---------------------------------------------------------------------------
// Merged fp32->bf16 converts + bias pack, one launch.
// regions (blocks): x[0,2048) Wq[2048,2560) Wk[2560,3072) Wv[3072,3584)
//                   Wr[3584,3592) Ws[3592,3593) biaspack[3593,3605)
// ---------------------------------------------------------------------------
__device__ __forceinline__ void cvt8(const float* __restrict__ s,
                                     unsigned short* __restrict__ d, int i) {
    const float* p = s + (size_t)i * 8;
    float4 a = *(const float4*)p;
    float4 b = *(const float4*)(p + 4);
    unsigned int u0 = pkbf16(a.x, a.y), u1 = pkbf16(a.z, a.w);
    unsigned int u2 = pkbf16(b.x, b.y), u3 = pkbf16(b.z, b.w);
    uint4 o = {u0, u1, u2, u3};
    *(uint4*)&d[(size_t)i * 8] = o;
}

__global__ __launch_bounds__(256) void cvt_main(
    const float* __restrict__ x,  const float* __restrict__ Wq,
    const float* __restrict__ Wk, const float* __restrict__ Wv,
    const float* __restrict__ Wr, const float* __restrict__ Ws,
    const float* __restrict__ bq, const float* __restrict__ bk,
    const float* __restrict__ bv,
    unsigned short* __restrict__ xb, unsigned short* __restrict__ wqkv,
    unsigned short* __restrict__ wg, float* __restrict__ bqkv)
{
    int blk = blockIdx.x, t = threadIdx.x;
    if (blk < 2048)      cvt8(x,  xb,             blk * 256 + t);
    else if (blk < 2560) cvt8(Wq, wqkv,           (blk - 2048) * 256 + t);
    else if (blk < 3072) cvt8(Wk, wqkv + 1048576, (blk - 2560) * 256 + t);
    else if (blk < 3584) cvt8(Wv, wqkv + 2097152, (blk - 3072) * 256 + t);
    else if (blk < 3592) { int i = (blk - 3584) * 256 + t; if (i < 1920) cvt8(Wr, wg, i); }
    else if (blk < 3593) { int i = t; cvt8(Ws, wg + 15360, i); }
    else {
        int i = (blk - 3593) * 256 + t;  // 0..3071
        bqkv[i] = (i < 1024) ? bq[i] : (i < 2048) ? bk[i - 1024] : bv[i - 2048];
    }
}

// standalone cvt (for Wp, launched after QKV GEMM frees its region)
__global__ __launch_bounds__(256) void cvt_kernel(
    const float* __restrict__ src, unsigned short* __restrict__ dst, int n8)
{
    int i = blockIdx.x * 256 + threadIdx.x;
    if (i < n8) cvt8(src, dst, i);
}

// ---------------------------------------------------------------------------
// QKV GEMM: C = xb[4096][1024] * Wqkv[3072][1024]^T + bias.
// 128x128 tile, BK=64, swizzled LDS + global_load_lds.
// n0<1024 -> Q[tok][ch]; <2048 -> K[tok][ch]; else V written TRANSPOSED to
// Vt[b,h,d,tok] (acc's 4 consecutive tokens per lane = contiguous, 8B packs).
// ---------------------------------------------------------------------------
__global__ __launch_bounds__(256) void qkv_gemm(
    const unsigned short* __restrict__ A,
    const unsigned short* __restrict__ Bw,
    const float* __restrict__ bias,
    unsigned short* __restrict__ Q, unsigned short* __restrict__ K,
    unsigned short* __restrict__ Vt)
{
    __shared__ __attribute__((aligned(16))) unsigned short As[128 * 64];
    __shared__ __attribute__((aligned(16))) unsigned short Bs[128 * 64];
    const int t = threadIdx.x;
    const int wave = t >> 6, lane = t & 63;
    const int m0 = blockIdx.x * 128, n0 = blockIdx.y * 128;
    const int wm = (wave >> 1) * 64, wn = (wave & 1) * 64;
    const int lr = lane & 15, lq = lane >> 4;
    const int srow = lane >> 3;
    const int scol = (((lane & 7) ^ srow) << 3);

    f32x4 acc[4][4];
#pragma unroll
    for (int i = 0; i < 4; ++i)
#pragma unroll
        for (int j = 0; j < 4; ++j) acc[i][j] = (f32x4){0.f, 0.f, 0.f, 0.f};

    for (int k0 = 0; k0 < 1024; k0 += 64) {
        __syncthreads();
#pragma unroll
        for (int i = 0; i < 4; ++i) {
            int rb = wave * 32 + i * 8;
            gl_lds16(&A[(size_t)(m0 + rb + srow) * 1024 + k0 + scol], &As[rb * 64]);
            gl_lds16(&Bw[(size_t)(n0 + rb + srow) * 1024 + k0 + scol], &Bs[rb * 64]);
        }
        __syncthreads();
#pragma unroll
        for (int kk = 0; kk < 64; kk += 32) {
            const int po = ((((kk >> 3) + lq) ^ (lr & 7)) << 3);
            s16x8 af[4], bf[4];
#pragma unroll
            for (int i = 0; i < 4; ++i)
                af[i] = *(const s16x8*)&As[(wm + i * 16 + lr) * 64 + po];
#pragma unroll
            for (int j = 0; j < 4; ++j)
                bf[j] = *(const s16x8*)&Bs[(wn + j * 16 + lr) * 64 + po];
#pragma unroll
            for (int i = 0; i < 4; ++i)
#pragma unroll
                for (int j = 0; j < 4; ++j)
                    acc[i][j] = __builtin_amdgcn_mfma_f32_16x16x32_bf16(af[i], bf[j], acc[i][j], 0, 0, 0);
        }
    }
    const int kind = n0 >> 10;        // 0=Q 1=K 2=V
    const int nc = n0 & 1023;
    if (kind < 2) {
        unsigned short* Cm = kind ? K : Q;
#pragma unroll
        for (int j = 0; j < 4; ++j) {
            int cl = wn + j * 16 + lr;
            float bv = bias[n0 + cl];
#pragma unroll
            for (int i = 0; i < 4; ++i) {
                int rowb = m0 + wm + i * 16 + lq * 4;
                unsigned int u0 = pkbf16(acc[i][j][0] + bv, acc[i][j][1] + bv);
                unsigned int u1 = pkbf16(acc[i][j][2] + bv, acc[i][j][3] + bv);
                Cm[(size_t)(rowb + 0) * 1024 + nc + cl] = (unsigned short)u0;
                Cm[(size_t)(rowb + 1) * 1024 + nc + cl] = (unsigned short)(u0 >> 16);
                Cm[(size_t)(rowb + 2) * 1024 + nc + cl] = (unsigned short)u1;
                Cm[(size_t)(rowb + 3) * 1024 + nc + cl] = (unsigned short)(u1 >> 16);
            }
        }
    } else {
        // V -> Vt[b,h,d,tok]: 4 consecutive tokens per lane = 8B contiguous
        const int bb = m0 >> 11;
#pragma unroll
        for (int j = 0; j < 4; ++j) {
            int col = nc + wn + j * 16 + lr;      // channel 0..1023
            int hh = col >> 6, dd = col & 63;
            float bv = bias[n0 + wn + j * 16 + lr];
#pragma unroll
            for (int i = 0; i < 4; ++i) {
                int tokb = m0 + wm + i * 16 + lq * 4;
                int tloc = tokb & 2047;
                uint2 u;
                u.x = pkbf16(acc[i][j][0] + bv, acc[i][j][1] + bv);
                u.y = pkbf16(acc[i][j][2] + bv, acc[i][j][3] + bv);
                *(uint2*)&Vt[((size_t)(bb * 16 + hh) * 64 + dd) * 2048 + tloc] = u;
            }
        }
    }
}

// ---------------------------------------------------------------------------
// Flash attention with FUSED q-scale. 64 q-rows/block for one (b,h).
// m=0 softmax (bounded logits), deferred l-reduce, swizzled LDS.
// ---------------------------------------------------------------------------
__global__ __launch_bounds__(256) void attn_kernel(
    const unsigned short* __restrict__ Q,   // raw q [B*N][C]
    const unsigned short* __restrict__ Kb,  // [B*N][C]
    const unsigned short* __restrict__ Vt,  // [B][H][64][N]
    const float* __restrict__ temp,
    const float* __restrict__ qe,
    unsigned short* __restrict__ Hout)      // [B*N][C]
{
    __shared__ __attribute__((aligned(16))) unsigned short Qs[64 * 64];
    __shared__ __attribute__((aligned(16))) unsigned short Ks[64 * 64];
    __shared__ __attribute__((aligned(16))) unsigned short Vs[64 * 64];
    __shared__ __attribute__((aligned(16))) unsigned short Ps[64 * 72];
    const int t = threadIdx.x, wave = t >> 6, lane = t & 63;
    const int lr = lane & 15, lq = lane >> 4;
    const int bh = blockIdx.y, b = bh >> 4, h = bh & 15;
    const int q0 = blockIdx.x * 64;
    const int srow = lane >> 3;
    const int scol = (((lane & 7) ^ srow) << 3);

    // stage raw Q (swizzled)
#pragma unroll
    for (int i = 0; i < 2; ++i) {
        int rb = wave * 16 + i * 8;
        gl_lds16(&Q[(size_t)(b * 2048 + q0 + rb + srow) * 1024 + h * 64 + scol], &Qs[rb * 64]);
    }
    __syncthreads();

    // fused q-scale: q' = (q/||q|| + qe[h]) * softplus(temp[h]) / (8 ln2)
    {
        const int qr = t >> 2, part = t & 3;
        const int pb0 = (((part * 2) ^ (qr & 7)) << 3);
        const int pb1 = (((part * 2 + 1) ^ (qr & 7)) << 3);
        s16x8 a = *(const s16x8*)&Qs[qr * 64 + pb0];
        s16x8 c = *(const s16x8*)&Qs[qr * 64 + pb1];
        float va[8], vc[8];
        float ss = 0.f;
#pragma unroll
        for (int e = 0; e < 8; ++e) {
            va[e] = b2f((unsigned short)a[e]); vc[e] = b2f((unsigned short)c[e]);
            ss += va[e] * va[e] + vc[e] * vc[e];
        }
        ss += __shfl_xor(ss, 1); ss += __shfl_xor(ss, 2);
        float rn = rsqrtf(ss);
        float tv = temp[h];
        float sp = ((tv > 20.f) ? tv : log1pf(__expf(tv))) * 0.18033688f;
        const float* qh = qe + h * 64 + part * 16;
        s16x8 oa, oc;
#pragma unroll
        for (int e = 0; e < 8; e += 2) {
            unsigned int u0 = pkbf16((va[e] * rn + qh[e]) * sp, (va[e + 1] * rn + qh[e + 1]) * sp);
            unsigned int u1 = pkbf16((vc[e] * rn + qh[8 + e]) * sp, (vc[e + 1] * rn + qh[8 + e + 1]) * sp);
            oa[e] = (short)u0; oa[e + 1] = (short)(u0 >> 16);
            oc[e] = (short)u1; oc[e + 1] = (short)(u1 >> 16);
        }
        *(s16x8*)&Qs[qr * 64 + pb0] = oa;
        *(s16x8*)&Qs[qr * 64 + pb1] = oc;
    }

    f32x4 accO[4];
#pragma unroll
    for (int j = 0; j < 4; ++j) accO[j] = (f32x4){0.f, 0.f, 0.f, 0.f};
    float lsum[4] = {0.f, 0.f, 0.f, 0.f};

    for (int kc = 0; kc < 2048; kc += 64) {
        __syncthreads();
#pragma unroll
        for (int i = 0; i < 2; ++i) {
            int rb = wave * 16 + i * 8;
            gl_lds16(&Kb[(size_t)(b * 2048 + kc + rb + srow) * 1024 + h * 64 + scol], &Ks[rb * 64]);
            gl_lds16(&Vt[((size_t)(b * 16 + h) * 64 + rb + srow) * 2048 + kc + scol], &Vs[rb * 64]);
        }
        __syncthreads();

        f32x4 s[4];
#pragma unroll
        for (int j = 0; j < 4; ++j) s[j] = (f32x4){0.f, 0.f, 0.f, 0.f};
#pragma unroll
        for (int kk = 0; kk < 64; kk += 32) {
            const int po = ((((kk >> 3) + lq) ^ (lr & 7)) << 3);
            s16x8 aq = *(const s16x8*)&Qs[(wave * 16 + lr) * 64 + po];
#pragma unroll
            for (int j = 0; j < 4; ++j) {
                s16x8 bk = *(const s16x8*)&Ks[(j * 16 + lr) * 64 + po];
                s[j] = __builtin_amdgcn_mfma_f32_16x16x32_bf16(aq, bk, s[j], 0, 0, 0);
            }
        }

        // p = 2^s; packed bf16 convert; row sums deferred
#pragma unroll
        for (int r = 0; r < 4; ++r) {
            float p0 = fast_exp2(s[0][r]), p1 = fast_exp2(s[1][r]);
            float p2 = fast_exp2(s[2][r]), p3 = fast_exp2(s[3][r]);
            lsum[r] += (p0 + p1) + (p2 + p3);
            unsigned int ua = pkbf16(p0, p1), ub = pkbf16(p2, p3);
            int base = (wave * 16 + lq * 4 + r) * 72 + lr;
            Ps[base]      = (unsigned short)ua;
            Ps[base + 16] = (unsigned short)(ua >> 16);
            Ps[base + 32] = (unsigned short)ub;
            Ps[base + 48] = (unsigned short)(ub >> 16);
        }

        // O += P * V   (Ps wave-private, no barrier)
#pragma unroll
        for (int kk = 0; kk < 64; kk += 32) {
            const int po = ((((kk >> 3) + lq) ^ (lr & 7)) << 3);
            s16x8 ap = *(const s16x8*)&Ps[(wave * 16 + lr) * 72 + kk + lq * 8];
#pragma unroll
            for (int j = 0; j < 4; ++j) {
                s16x8 bv = *(const s16x8*)&Vs[(j * 16 + lr) * 64 + po];
                accO[j] = __builtin_amdgcn_mfma_f32_16x16x32_bf16(ap, bv, accO[j], 0, 0, 0);
            }
        }
    }

#pragma unroll
    for (int r = 0; r < 4; ++r) {
        float l = lsum[r];
        l += __shfl_xor(l, 1); l += __shfl_xor(l, 2);
        l += __shfl_xor(l, 4); l += __shfl_xor(l, 8);
        float inv = 1.f / l;
        int row = q0 + wave * 16 + lq * 4 + r;
        size_t ob = (size_t)(b * 2048 + row) * 1024 + h * 64 + lr;
        unsigned int u0 = pkbf16(accO[0][r] * inv, accO[1][r] * inv);
        unsigned int u1 = pkbf16(accO[2][r] * inv, accO[3][r] * inv);
        Hout[ob]      = (unsigned short)u0;
        Hout[ob + 16] = (unsigned short)(u0 >> 16);
        Hout[ob + 32] = (unsigned short)u1;
        Hout[ob + 48] = (unsigned short)(u1 >> 16);
    }
}

// ---------------------------------------------------------------------------
// Gate logits GEMM: logits[4096][32] = h[4096][1024] * Wg[17(->32)][1024]^T
// (fp32 out, no bias; cols 17..31 garbage/unused; Wg rows clamped to 16)
// ---------------------------------------------------------------------------
__global__ __launch_bounds__(256) void gl_gemm(
    const unsigned short* __restrict__ Hb,
    const unsigned short* __restrict__ Wg,
    float* __restrict__ logits)
{
    __shared__ __attribute__((aligned(16))) unsigned short As[128 * 64];
    __shared__ __attribute__((aligned(16))) unsigned short Gs[32 * 64];
    const int t = threadIdx.x, wave = t >> 6, lane = t & 63;
    const int lr = lane & 15, lq = lane >> 4;
    const int m0 = blockIdx.x * 128;
    const int srow = lane >> 3;
    const int scol = (((lane & 7) ^ srow) << 3);

    f32x4 acc[2][2];
#pragma unroll
    for (int i = 0; i < 2; ++i)
#pragma unroll
        for (int j = 0; j < 2; ++j) acc[i][j] = (f32x4){0.f, 0.f, 0.f, 0.f};

    for (int k0 = 0; k0 < 1024; k0 += 64) {
        __syncthreads();
#pragma unroll
        for (int i = 0; i < 4; ++i) {
            int rb = wave * 32 + i * 8;
            gl_lds16(&Hb[(size_t)(m0 + rb + srow) * 1024 + k0 + scol], &As[rb * 64]);
        }
        {
            int row = wave * 8 + srow;
            int wr = (row > 16) ? 16 : row;   // clamp: no OOB
            gl_lds16(&Wg[(size_t)wr * 1024 + k0 + scol], &Gs[wave * 8 * 64]);
        }
        __syncthreads();
#pragma unroll
        for (int kk = 0; kk < 64; kk += 32) {
            const int po = ((((kk >> 3) + lq) ^ (lr & 7)) << 3);
            s16x8 af[2], gf[2];
#pragma unroll
            for (int i = 0; i < 2; ++i)
                af[i] = *(const s16x8*)&As[(wave * 32 + i * 16 + lr) * 64 + po];
#pragma unroll
            for (int j = 0; j < 2; ++j)
                gf[j] = *(const s16x8*)&Gs[(j * 16 + lr) * 64 + po];
#pragma unroll
            for (int i = 0; i < 2; ++i)
#pragma unroll
                for (int j = 0; j < 2; ++j)
                    acc[i][j] = __builtin_amdgcn_mfma_f32_16x16x32_bf16(af[i], gf[j], acc[i][j], 0, 0, 0);
        }
    }
#pragma unroll
    for (int i = 0; i < 2; ++i)
#pragma unroll
        for (int j = 0; j < 2; ++j) {
            int col = j * 16 + lr;
            int rowb = m0 + wave * 32 + i * 16 + lq * 4;
#pragma unroll
            for (int r = 0; r < 4; ++r)
                logits[(size_t)(rowb + r) * 32 + col] = acc[i][j][r];
        }
}

// ---------------------------------------------------------------------------
// Gate apply: g = 2*sw0 + 6*sw1*top3sum; h <- h*g. One token/block.
// ---------------------------------------------------------------------------
__global__ __launch_bounds__(256) void gate_apply(
    unsigned short* __restrict__ Hb,
    const float* __restrict__ logits,
    const float* __restrict__ br,
    const float* __restrict__ bs)
{
    const int tok = blockIdx.x, t = threadIdx.x;
    float lg[17];
#pragma unroll
    for (int j = 0; j < 17; ++j)
        lg[j] = logits[(size_t)tok * 32 + j] + ((j < 15) ? br[j] : bs[j - 15]);
    float mx = lg[0];
#pragma unroll
    for (int j = 1; j < 15; ++j) mx = fmaxf(mx, lg[j]);
    float sum = 0.f, v1 = -1.f, v2 = -1.f, v3 = -1.f;
#pragma unroll
    for (int j = 0; j < 15; ++j) {
        float e = __expf(lg[j] - mx);
        sum += e;
        if (e > v1)      { v3 = v2; v2 = v1; v1 = e; }
        else if (e > v2) { v3 = v2; v2 = e; }
        else if (e > v3) { v3 = e; }
    }
    float tops = (v1 + v2 + v3) / sum;
    float sm = fmaxf(lg[15], lg[16]);
    float e0 = __expf(lg[15] - sm), e1 = __expf(lg[16] - sm);
    float inv = 1.f / (e0 + e1);
    float g = 2.f * (e0 * inv) + 6.f * (e1 * inv) * tops;

    size_t base = (size_t)tok * 1024 + t * 4;
    ushort4 hr = *(const ushort4*)&Hb[base];
    unsigned int u0 = pkbf16(b2f(hr.x) * g, b2f(hr.y) * g);
    unsigned int u1 = pkbf16(b2f(hr.z) * g, b2f(hr.w) * g);
    uint2 o = {u0, u1};
    *(uint2*)&Hb[base] = o;
}

// ---------------------------------------------------------------------------
// Out-proj GEMM: out[4096][1024] = h*Wp^T + bp (fp32 out).
// 64x128 tile -> grid 512 = 2 blocks/CU.
// ---------------------------------------------------------------------------
__global__ __launch_bounds__(256) void gemm64_out(
    const unsigned short* __restrict__ A,
    const unsigned short* __restrict__ Bw,
    const float* __restrict__ bias,
    float* __restrict__ C)
{
    __shared__ __attribute__((aligned(16))) unsigned short As[64 * 64];
    __shared__ __attribute__((aligned(16))) unsigned short Bs[128 * 64];
    const int t = threadIdx.x, wave = t >> 6, lane = t & 63;
    const int lr = lane & 15, lq = lane >> 4;
    const int m0 = blockIdx.x * 64, n0 = blockIdx.y * 128;
    const int wm = (wave >> 1) * 32, wn = (wave & 1) * 64;
    const int srow = lane >> 3;
    const int scol = (((lane & 7) ^ srow) << 3);

    f32x4 acc[2][4];
#pragma unroll
    for (int i = 0; i < 2; ++i)
#pragma unroll
        for (int j = 0; j < 4; ++j) acc[i][j] = (f32x4){0.f, 0.f, 0.f, 0.f};

    for (int k0 = 0; k0 < 1024; k0 += 64) {
        __syncthreads();
#pragma unroll
        for (int i = 0; i < 2; ++i) {
            int rb = wave * 16 + i * 8;
            gl_lds16(&A[(size_t)(m0 + rb + srow) * 1024 + k0 + scol], &As[rb * 64]);
        }
#pragma unroll
        for (int i = 0; i < 4; ++i) {
            int rb = wave * 32 + i * 8;
            gl_lds16(&Bw[(size_t)(n0 + rb + srow) * 1024 + k0 + scol], &Bs[rb * 64]);
        }
        __syncthreads();
#pragma unroll
        for (int kk = 0; kk < 64; kk += 32) {
            const int po = ((((kk >> 3) + lq) ^ (lr & 7)) << 3);
            s16x8 af[2], bf[4];
#pragma unroll
            for (int i = 0; i < 2; ++i)
                af[i] = *(const s16x8*)&As[(wm + i * 16 + lr) * 64 + po];
#pragma unroll
            for (int j = 0; j < 4; ++j)
                bf[j] = *(const s16x8*)&Bs[(wn + j * 16 + lr) * 64 + po];
#pragma unroll
            for (int i = 0; i < 2; ++i)
#pragma unroll
                for (int j = 0; j < 4; ++j)
                    acc[i][j] = __builtin_amdgcn_mfma_f32_16x16x32_bf16(af[i], bf[j], acc[i][j], 0, 0, 0);
        }
    }
#pragma unroll
    for (int j = 0; j < 4; ++j) {
        int col = n0 + wn + j * 16 + lr;
        float bv = bias[col];
#pragma unroll
        for (int i = 0; i < 2; ++i) {
            int rowb = m0 + wm + i * 16 + lq * 4;
#pragma unroll
            for (int r = 0; r < 4; ++r)
                C[(size_t)(rowb + r) * 1024 + col] = acc[i][j][r] + bv;
        }
    }
}

// ---------------------------------------------------------------------------
extern "C" void kernel_launch(void* const* d_in, const int* in_sizes, int n_in,
                              void* d_out, int out_size, void* d_ws, size_t ws_size,
                              hipStream_t stream)
{
    (void)in_sizes; (void)n_in; (void)out_size; (void)ws_size;
    const float* x   = (const float*)d_in[0];
    const float* Wq  = (const float*)d_in[1];
    const float* bq  = (const float*)d_in[2];
    const float* Wk  = (const float*)d_in[3];
    const float* bk  = (const float*)d_in[4];
    const float* Wv  = (const float*)d_in[5];
    const float* bv  = (const float*)d_in[6];
    const float* Wp  = (const float*)d_in[7];
    const float* bp  = (const float*)d_in[8];
    const float* Wr  = (const float*)d_in[9];
    const float* br  = (const float*)d_in[10];
    const float* Ws  = (const float*)d_in[11];
    const float* bs  = (const float*)d_in[12];
    const float* temperature = (const float*)d_in[13];
    const float* qe  = (const float*)d_in[14];
    float* out = (float*)d_out;

    const size_t MB = 1048576;
    unsigned short* qb     = (unsigned short*)d_ws;                     // 8 MiB
    unsigned short* kb     = (unsigned short*)((char*)d_ws + 8 * MB);   // 8 MiB
    unsigned short* hb     = (unsigned short*)((char*)d_ws + 16 * MB);  // 8 MiB (h)
    unsigned short* wqkv   = (unsigned short*)((char*)d_ws + 24 * MB);  // 6 MiB
    unsigned short* wpb    = wqkv;                                      // reuse post-QKV
    unsigned short* wg     = (unsigned short*)((char*)d_ws + 30 * MB);  // 34 KiB
    float*          bqkv   = (float*)((char*)d_ws + 30 * MB + 65536);   // 12 KiB
    float*          logits = (float*)((char*)d_ws + 30 * MB + 131072);  // 512 KiB
    // d_out doubles as scratch until the final GEMM:
    unsigned short* xb = (unsigned short*)d_out;                        // 8 MiB
    unsigned short* vt = xb + 4 * MB;                                   // 8 MiB V^T

    dim3 blk(256);
    cvt_main<<<dim3(3605), blk, 0, stream>>>(x, Wq, Wk, Wv, Wr, Ws, bq, bk, bv,
                                             xb, wqkv, wg, bqkv);
    qkv_gemm<<<dim3(32, 24), blk, 0, stream>>>(xb, wqkv, bqkv, qb, kb, vt);
    cvt_kernel<<<dim3(512), blk, 0, stream>>>(Wp, wpb, 131072);
    attn_kernel<<<dim3(32, 32), blk, 0, stream>>>(qb, kb, vt, temperature, qe, hb);
    gl_gemm<<<dim3(32), blk, 0, stream>>>(hb, wg, logits);
    gate_apply<<<dim3(4096), blk, 0, stream>>>(hb, logits, br, bs);
    gemm64_out<<<dim3(64, 8), blk, 0, stream>>>(hb, wpb, bp, out);
}

// Round 6
// 240.144 us; speedup vs baseline: 1.9054x; 1.0683x over previous
//
#include <hip/hip_runtime.h>
#include <hip/hip_bf16.h>

typedef short s16x8 __attribute__((ext_vector_type(8)));
typedef float f32x4 __attribute__((ext_vector_type(4)));

__device__ __forceinline__ float b2f(unsigned short u) {
    union { unsigned int i; float f; } v;
    v.i = ((unsigned int)u) << 16;
    return v.f;
}
__device__ __forceinline__ unsigned short f2b(float f) {
    unsigned int x = __builtin_bit_cast(unsigned int, f);
    unsigned int r = (x + 0x7fffu + ((x >> 16) & 1u)) >> 16;
    return (unsigned short)r;
}
// packed fp32x2 -> bf16x2 (v_cvt_pk_bf16_f32 on gfx950); lo = a, hi = b
__device__ __forceinline__ unsigned int pkbf16(float a, float b) {
    union { __hip_bfloat162 h; unsigned int u; } v;
    v.h = __float22bfloat162_rn(make_float2(a, b));
    return v.u;
}
// raw v_exp_f32 — libm exp2f adds clamp/scale VALU (measured regression r5)
__device__ __forceinline__ float fast_exp2(float x) {
#if __has_builtin(__builtin_amdgcn_exp2f)
    return __builtin_amdgcn_exp2f(x);
#else
    return exp2f(x);
#endif
}

// async global->LDS, 16B/lane; LDS dest = wave-uniform base + lane*16
__device__ __forceinline__ void gl_lds16(const unsigned short* g, unsigned short* l) {
    __builtin_amdgcn_global_load_lds(
        (const __attribute__((address_space(1))) void*)g,
        (__attribute__((address_space(3))) void*)l, 16, 0, 0);
}

// XOR-swizzle: 16B block c of row r lives at physical block c^(r%8).

// ---------------------------------------------------------------------------
// Merged fp32->bf16 converts + bias pack, one launch.
// ---------------------------------------------------------------------------
__device__ __forceinline__ void cvt8(const float* __restrict__ s,
                                     unsigned short* __restrict__ d, int i) {
    const float* p = s + (size_t)i * 8;
    float4 a = *(const float4*)p;
    float4 b = *(const float4*)(p + 4);
    unsigned int u0 = pkbf16(a.x, a.y), u1 = pkbf16(a.z, a.w);
    unsigned int u2 = pkbf16(b.x, b.y), u3 = pkbf16(b.z, b.w);
    uint4 o = {u0, u1, u2, u3};
    *(uint4*)&d[(size_t)i * 8] = o;
}

__global__ __launch_bounds__(256) void cvt_main(
    const float* __restrict__ x,  const float* __restrict__ Wq,
    const float* __restrict__ Wk, const float* __restrict__ Wv,
    const float* __restrict__ Wr, const float* __restrict__ Ws,
    const float* __restrict__ bq, const float* __restrict__ bk,
    const float* __restrict__ bv,
    unsigned short* __restrict__ xb, unsigned short* __restrict__ wqkv,
    unsigned short* __restrict__ wg, float* __restrict__ bqkv)
{
    int blk = blockIdx.x, t = threadIdx.x;
    if (blk < 2048)      cvt8(x,  xb,             blk * 256 + t);
    else if (blk < 2560) cvt8(Wq, wqkv,           (blk - 2048) * 256 + t);
    else if (blk < 3072) cvt8(Wk, wqkv + 1048576, (blk - 2560) * 256 + t);
    else if (blk < 3584) cvt8(Wv, wqkv + 2097152, (blk - 3072) * 256 + t);
    else if (blk < 3592) { int i = (blk - 3584) * 256 + t; if (i < 1920) cvt8(Wr, wg, i); }
    else if (blk < 3593) { int i = t; cvt8(Ws, wg + 15360, i); }
    else {
        int i = (blk - 3593) * 256 + t;  // 0..3071
        bqkv[i] = (i < 1024) ? bq[i] : (i < 2048) ? bk[i - 1024] : bv[i - 2048];
    }
}

// standalone cvt (for Wp, launched after QKV GEMM frees its region)
__global__ __launch_bounds__(256) void cvt_kernel(
    const float* __restrict__ src, unsigned short* __restrict__ dst, int n8)
{
    int i = blockIdx.x * 256 + threadIdx.x;
    if (i < n8) cvt8(src, dst, i);
}

// ---------------------------------------------------------------------------
// QKV GEMM: C = xb[4096][1024] * Wqkv[3072][1024]^T + bias.
// 128x128 tile, BK=64, swizzled LDS + global_load_lds.
// n0<1024 -> Q; <2048 -> K; else V written transposed to Vt[b,h,d,tok].
// ---------------------------------------------------------------------------
__global__ __launch_bounds__(256) void qkv_gemm(
    const unsigned short* __restrict__ A,
    const unsigned short* __restrict__ Bw,
    const float* __restrict__ bias,
    unsigned short* __restrict__ Q, unsigned short* __restrict__ K,
    unsigned short* __restrict__ Vt)
{
    __shared__ __attribute__((aligned(16))) unsigned short As[128 * 64];
    __shared__ __attribute__((aligned(16))) unsigned short Bs[128 * 64];
    const int t = threadIdx.x;
    const int wave = t >> 6, lane = t & 63;
    const int m0 = blockIdx.x * 128, n0 = blockIdx.y * 128;
    const int wm = (wave >> 1) * 64, wn = (wave & 1) * 64;
    const int lr = lane & 15, lq = lane >> 4;
    const int srow = lane >> 3;
    const int scol = (((lane & 7) ^ srow) << 3);

    f32x4 acc[4][4];
#pragma unroll
    for (int i = 0; i < 4; ++i)
#pragma unroll
        for (int j = 0; j < 4; ++j) acc[i][j] = (f32x4){0.f, 0.f, 0.f, 0.f};

    for (int k0 = 0; k0 < 1024; k0 += 64) {
        __syncthreads();
#pragma unroll
        for (int i = 0; i < 4; ++i) {
            int rb = wave * 32 + i * 8;
            gl_lds16(&A[(size_t)(m0 + rb + srow) * 1024 + k0 + scol], &As[rb * 64]);
            gl_lds16(&Bw[(size_t)(n0 + rb + srow) * 1024 + k0 + scol], &Bs[rb * 64]);
        }
        __syncthreads();
#pragma unroll
        for (int kk = 0; kk < 64; kk += 32) {
            const int po = ((((kk >> 3) + lq) ^ (lr & 7)) << 3);
            s16x8 af[4], bf[4];
#pragma unroll
            for (int i = 0; i < 4; ++i)
                af[i] = *(const s16x8*)&As[(wm + i * 16 + lr) * 64 + po];
#pragma unroll
            for (int j = 0; j < 4; ++j)
                bf[j] = *(const s16x8*)&Bs[(wn + j * 16 + lr) * 64 + po];
#pragma unroll
            for (int i = 0; i < 4; ++i)
#pragma unroll
                for (int j = 0; j < 4; ++j)
                    acc[i][j] = __builtin_amdgcn_mfma_f32_16x16x32_bf16(af[i], bf[j], acc[i][j], 0, 0, 0);
        }
    }
    const int kind = n0 >> 10;        // 0=Q 1=K 2=V
    const int nc = n0 & 1023;
    if (kind < 2) {
        unsigned short* Cm = kind ? K : Q;
#pragma unroll
        for (int j = 0; j < 4; ++j) {
            int cl = wn + j * 16 + lr;
            float bv = bias[n0 + cl];
#pragma unroll
            for (int i = 0; i < 4; ++i) {
                int rowb = m0 + wm + i * 16 + lq * 4;
                unsigned int u0 = pkbf16(acc[i][j][0] + bv, acc[i][j][1] + bv);
                unsigned int u1 = pkbf16(acc[i][j][2] + bv, acc[i][j][3] + bv);
                Cm[(size_t)(rowb + 0) * 1024 + nc + cl] = (unsigned short)u0;
                Cm[(size_t)(rowb + 1) * 1024 + nc + cl] = (unsigned short)(u0 >> 16);
                Cm[(size_t)(rowb + 2) * 1024 + nc + cl] = (unsigned short)u1;
                Cm[(size_t)(rowb + 3) * 1024 + nc + cl] = (unsigned short)(u1 >> 16);
            }
        }
    } else {
        // V -> Vt[b,h,d,tok]: 4 consecutive tokens per lane = 8B contiguous
        const int bb = m0 >> 11;
#pragma unroll
        for (int j = 0; j < 4; ++j) {
            int col = nc + wn + j * 16 + lr;      // channel 0..1023
            int hh = col >> 6, dd = col & 63;
            float bv = bias[n0 + wn + j * 16 + lr];
#pragma unroll
            for (int i = 0; i < 4; ++i) {
                int tokb = m0 + wm + i * 16 + lq * 4;
                int tloc = tokb & 2047;
                uint2 u;
                u.x = pkbf16(acc[i][j][0] + bv, acc[i][j][1] + bv);
                u.y = pkbf16(acc[i][j][2] + bv, acc[i][j][3] + bv);
                *(uint2*)&Vt[((size_t)(bb * 16 + hh) * 64 + dd) * 2048 + tloc] = u;
            }
        }
    }
}

// ---------------------------------------------------------------------------
// Flash attention, 128-q tile (4 waves x 32 q-rows), fused q-scale,
// m=0 softmax, deferred l-reduce, swizzled Qs/Ks/Vs, Ps wave-private.
// ---------------------------------------------------------------------------
__global__ __launch_bounds__(256) void attn_kernel(
    const unsigned short* __restrict__ Q,   // raw q [B*N][C]
    const unsigned short* __restrict__ Kb,  // [B*N][C]
    const unsigned short* __restrict__ Vt,  // [B][H][64][N]
    const float* __restrict__ temp,
    const float* __restrict__ qe,
    unsigned short* __restrict__ Hout)      // [B*N][C]
{
    __shared__ __attribute__((aligned(16))) unsigned short Qs[128 * 64];   // 16 KB
    __shared__ __attribute__((aligned(16))) unsigned short Ks[64 * 64];    // 8 KB
    __shared__ __attribute__((aligned(16))) unsigned short Vs[64 * 64];    // 8 KB
    __shared__ __attribute__((aligned(16))) unsigned short Ps[128 * 72];   // 18 KB
    const int t = threadIdx.x, wave = t >> 6, lane = t & 63;
    const int lr = lane & 15, lq = lane >> 4;
    const int bh = blockIdx.y, b = bh >> 4, h = bh & 15;
    const int q0 = blockIdx.x * 128;
    const int srow = lane >> 3;
    const int scol = (((lane & 7) ^ srow) << 3);

    // stage raw Q (swizzled): 128 rows, wave stages rows wave*32 + i*8
#pragma unroll
    for (int i = 0; i < 4; ++i) {
        int rb = wave * 32 + i * 8;
        gl_lds16(&Q[(size_t)(b * 2048 + q0 + rb + srow) * 1024 + h * 64 + scol], &Qs[rb * 64]);
    }
    __syncthreads();

    // fused q-scale: q' = (q/||q|| + qe[h]) * softplus(temp[h]) / (8 ln2)
    // thread handles row t>>1, half (t&1): 4 x 16B blocks = 32 elems
    {
        const int qr = t >> 1, part = t & 1;
        float tv = temp[h];
        float sp = ((tv > 20.f) ? tv : log1pf(__expf(tv))) * 0.18033688f;
        s16x8 frag[4];
        float v[4][8];
        float ss = 0.f;
#pragma unroll
        for (int c = 0; c < 4; ++c) {
            int pb = (((part * 4 + c) ^ (qr & 7)) << 3);
            frag[c] = *(const s16x8*)&Qs[qr * 64 + pb];
#pragma unroll
            for (int e = 0; e < 8; ++e) {
                v[c][e] = b2f((unsigned short)frag[c][e]);
                ss += v[c][e] * v[c][e];
            }
        }
        ss += __shfl_xor(ss, 1);
        float rn = rsqrtf(ss);
#pragma unroll
        for (int c = 0; c < 4; ++c) {
            const float* qh = qe + h * 64 + (part * 4 + c) * 8;
            s16x8 o;
#pragma unroll
            for (int e = 0; e < 8; e += 2) {
                unsigned int u = pkbf16((v[c][e] * rn + qh[e]) * sp,
                                        (v[c][e + 1] * rn + qh[e + 1]) * sp);
                o[e] = (short)u; o[e + 1] = (short)(u >> 16);
            }
            int pb = (((part * 4 + c) ^ (qr & 7)) << 3);
            *(s16x8*)&Qs[qr * 64 + pb] = o;
        }
    }

    f32x4 accO[2][4];
#pragma unroll
    for (int i = 0; i < 2; ++i)
#pragma unroll
        for (int j = 0; j < 4; ++j) accO[i][j] = (f32x4){0.f, 0.f, 0.f, 0.f};
    float lsum[2][4] = {{0.f, 0.f, 0.f, 0.f}, {0.f, 0.f, 0.f, 0.f}};

    for (int kc = 0; kc < 2048; kc += 64) {
        __syncthreads();
#pragma unroll
        for (int i = 0; i < 2; ++i) {
            int rb = wave * 16 + i * 8;
            gl_lds16(&Kb[(size_t)(b * 2048 + kc + rb + srow) * 1024 + h * 64 + scol], &Ks[rb * 64]);
            gl_lds16(&Vt[((size_t)(b * 16 + h) * 64 + rb + srow) * 2048 + kc + scol], &Vs[rb * 64]);
        }
        __syncthreads();

        // S = Q*K^T for wave's 32 q-rows (2 groups of 16) x 64 keys
        f32x4 s[2][4];
#pragma unroll
        for (int i = 0; i < 2; ++i)
#pragma unroll
            for (int j = 0; j < 4; ++j) s[i][j] = (f32x4){0.f, 0.f, 0.f, 0.f};
#pragma unroll
        for (int kk = 0; kk < 64; kk += 32) {
            const int po = ((((kk >> 3) + lq) ^ (lr & 7)) << 3);
            s16x8 aq[2], bk[4];
#pragma unroll
            for (int i = 0; i < 2; ++i)
                aq[i] = *(const s16x8*)&Qs[(wave * 32 + i * 16 + lr) * 64 + po];
#pragma unroll
            for (int j = 0; j < 4; ++j)
                bk[j] = *(const s16x8*)&Ks[(j * 16 + lr) * 64 + po];
#pragma unroll
            for (int i = 0; i < 2; ++i)
#pragma unroll
                for (int j = 0; j < 4; ++j)
                    s[i][j] = __builtin_amdgcn_mfma_f32_16x16x32_bf16(aq[i], bk[j], s[i][j], 0, 0, 0);
        }

        // p = 2^s; packed bf16; row sums deferred
#pragma unroll
        for (int i = 0; i < 2; ++i)
#pragma unroll
            for (int r = 0; r < 4; ++r) {
                float p0 = fast_exp2(s[i][0][r]), p1 = fast_exp2(s[i][1][r]);
                float p2 = fast_exp2(s[i][2][r]), p3 = fast_exp2(s[i][3][r]);
                lsum[i][r] += (p0 + p1) + (p2 + p3);
                unsigned int ua = pkbf16(p0, p1), ub = pkbf16(p2, p3);
                int base = (wave * 32 + i * 16 + lq * 4 + r) * 72 + lr;
                Ps[base]      = (unsigned short)ua;
                Ps[base + 16] = (unsigned short)(ua >> 16);
                Ps[base + 32] = (unsigned short)ub;
                Ps[base + 48] = (unsigned short)(ub >> 16);
            }

        // O += P * V   (Ps wave-private, no barrier)
#pragma unroll
        for (int kk = 0; kk < 64; kk += 32) {
            const int po = ((((kk >> 3) + lq) ^ (lr & 7)) << 3);
            s16x8 ap[2], bv[4];
#pragma unroll
            for (int i = 0; i < 2; ++i)
                ap[i] = *(const s16x8*)&Ps[(wave * 32 + i * 16 + lr) * 72 + kk + lq * 8];
#pragma unroll
            for (int j = 0; j < 4; ++j)
                bv[j] = *(const s16x8*)&Vs[(j * 16 + lr) * 64 + po];
#pragma unroll
            for (int i = 0; i < 2; ++i)
#pragma unroll
                for (int j = 0; j < 4; ++j)
                    accO[i][j] = __builtin_amdgcn_mfma_f32_16x16x32_bf16(ap[i], bv[j], accO[i][j], 0, 0, 0);
        }
    }

#pragma unroll
    for (int i = 0; i < 2; ++i)
#pragma unroll
        for (int r = 0; r < 4; ++r) {
            float l = lsum[i][r];
            l += __shfl_xor(l, 1); l += __shfl_xor(l, 2);
            l += __shfl_xor(l, 4); l += __shfl_xor(l, 8);
            float inv = 1.f / l;
            int row = q0 + wave * 32 + i * 16 + lq * 4 + r;
            size_t ob = (size_t)(b * 2048 + row) * 1024 + h * 64 + lr;
            unsigned int u0 = pkbf16(accO[i][0][r] * inv, accO[i][1][r] * inv);
            unsigned int u1 = pkbf16(accO[i][2][r] * inv, accO[i][3][r] * inv);
            Hout[ob]      = (unsigned short)u0;
            Hout[ob + 16] = (unsigned short)(u0 >> 16);
            Hout[ob + 32] = (unsigned short)u1;
            Hout[ob + 48] = (unsigned short)(u1 >> 16);
        }
}

// ---------------------------------------------------------------------------
// Gate logits GEMM: logits[4096][32] = h[4096][1024] * Wg[17(->32)][1024]^T
// ---------------------------------------------------------------------------
__global__ __launch_bounds__(256) void gl_gemm(
    const unsigned short* __restrict__ Hb,
    const unsigned short* __restrict__ Wg,
    float* __restrict__ logits)
{
    __shared__ __attribute__((aligned(16))) unsigned short As[128 * 64];
    __shared__ __attribute__((aligned(16))) unsigned short Gs[32 * 64];
    const int t = threadIdx.x, wave = t >> 6, lane = t & 63;
    const int lr = lane & 15, lq = lane >> 4;
    const int m0 = blockIdx.x * 128;
    const int srow = lane >> 3;
    const int scol = (((lane & 7) ^ srow) << 3);

    f32x4 acc[2][2];
#pragma unroll
    for (int i = 0; i < 2; ++i)
#pragma unroll
        for (int j = 0; j < 2; ++j) acc[i][j] = (f32x4){0.f, 0.f, 0.f, 0.f};

    for (int k0 = 0; k0 < 1024; k0 += 64) {
        __syncthreads();
#pragma unroll
        for (int i = 0; i < 4; ++i) {
            int rb = wave * 32 + i * 8;
            gl_lds16(&Hb[(size_t)(m0 + rb + srow) * 1024 + k0 + scol], &As[rb * 64]);
        }
        {
            int row = wave * 8 + srow;
            int wr = (row > 16) ? 16 : row;   // clamp: no OOB
            gl_lds16(&Wg[(size_t)wr * 1024 + k0 + scol], &Gs[wave * 8 * 64]);
        }
        __syncthreads();
#pragma unroll
        for (int kk = 0; kk < 64; kk += 32) {
            const int po = ((((kk >> 3) + lq) ^ (lr & 7)) << 3);
            s16x8 af[2], gf[2];
#pragma unroll
            for (int i = 0; i < 2; ++i)
                af[i] = *(const s16x8*)&As[(wave * 32 + i * 16 + lr) * 64 + po];
#pragma unroll
            for (int j = 0; j < 2; ++j)
                gf[j] = *(const s16x8*)&Gs[(j * 16 + lr) * 64 + po];
#pragma unroll
            for (int i = 0; i < 2; ++i)
#pragma unroll
                for (int j = 0; j < 2; ++j)
                    acc[i][j] = __builtin_amdgcn_mfma_f32_16x16x32_bf16(af[i], gf[j], acc[i][j], 0, 0, 0);
        }
    }
#pragma unroll
    for (int i = 0; i < 2; ++i)
#pragma unroll
        for (int j = 0; j < 2; ++j) {
            int col = j * 16 + lr;
            int rowb = m0 + wave * 32 + i * 16 + lq * 4;
#pragma unroll
            for (int r = 0; r < 4; ++r)
                logits[(size_t)(rowb + r) * 32 + col] = acc[i][j][r];
        }
}

// ---------------------------------------------------------------------------
// Gate apply: g = 2*sw0 + 6*sw1*top3sum; h <- h*g. One token/block.
// ---------------------------------------------------------------------------
__global__ __launch_bounds__(256) void gate_apply(
    unsigned short* __restrict__ Hb,
    const float* __restrict__ logits,
    const float* __restrict__ br,
    const float* __restrict__ bs)
{
    const int tok = blockIdx.x, t = threadIdx.x;
    float lg[17];
#pragma unroll
    for (int j = 0; j < 17; ++j)
        lg[j] = logits[(size_t)tok * 32 + j] + ((j < 15) ? br[j] : bs[j - 15]);
    float mx = lg[0];
#pragma unroll
    for (int j = 1; j < 15; ++j) mx = fmaxf(mx, lg[j]);
    float sum = 0.f, v1 = -1.f, v2 = -1.f, v3 = -1.f;
#pragma unroll
    for (int j = 0; j < 15; ++j) {
        float e = __expf(lg[j] - mx);
        sum += e;
        if (e > v1)      { v3 = v2; v2 = v1; v1 = e; }
        else if (e > v2) { v3 = v2; v2 = e; }
        else if (e > v3) { v3 = e; }
    }
    float tops = (v1 + v2 + v3) / sum;
    float sm = fmaxf(lg[15], lg[16]);
    float e0 = __expf(lg[15] - sm), e1 = __expf(lg[16] - sm);
    float inv = 1.f / (e0 + e1);
    float g = 2.f * (e0 * inv) + 6.f * (e1 * inv) * tops;

    size_t base = (size_t)tok * 1024 + t * 4;
    ushort4 hr = *(const ushort4*)&Hb[base];
    unsigned int u0 = pkbf16(b2f(hr.x) * g, b2f(hr.y) * g);
    unsigned int u1 = pkbf16(b2f(hr.z) * g, b2f(hr.w) * g);
    uint2 o = {u0, u1};
    *(uint2*)&Hb[base] = o;
}

// ---------------------------------------------------------------------------
// Out-proj GEMM: out[4096][1024] = h*Wp^T + bp (fp32 out). 64x128 tile.
// ---------------------------------------------------------------------------
__global__ __launch_bounds__(256) void gemm64_out(
    const unsigned short* __restrict__ A,
    const unsigned short* __restrict__ Bw,
    const float* __restrict__ bias,
    float* __restrict__ C)
{
    __shared__ __attribute__((aligned(16))) unsigned short As[64 * 64];
    __shared__ __attribute__((aligned(16))) unsigned short Bs[128 * 64];
    const int t = threadIdx.x, wave = t >> 6, lane = t & 63;
    const int lr = lane & 15, lq = lane >> 4;
    const int m0 = blockIdx.x * 64, n0 = blockIdx.y * 128;
    const int wm = (wave >> 1) * 32, wn = (wave & 1) * 64;
    const int srow = lane >> 3;
    const int scol = (((lane & 7) ^ srow) << 3);

    f32x4 acc[2][4];
#pragma unroll
    for (int i = 0; i < 2; ++i)
#pragma unroll
        for (int j = 0; j < 4; ++j) acc[i][j] = (f32x4){0.f, 0.f, 0.f, 0.f};

    for (int k0 = 0; k0 < 1024; k0 += 64) {
        __syncthreads();
#pragma unroll
        for (int i = 0; i < 2; ++i) {
            int rb = wave * 16 + i * 8;
            gl_lds16(&A[(size_t)(m0 + rb + srow) * 1024 + k0 + scol], &As[rb * 64]);
        }
#pragma unroll
        for (int i = 0; i < 4; ++i) {
            int rb = wave * 32 + i * 8;
            gl_lds16(&Bw[(size_t)(n0 + rb + srow) * 1024 + k0 + scol], &Bs[rb * 64]);
        }
        __syncthreads();
#pragma unroll
        for (int kk = 0; kk < 64; kk += 32) {
            const int po = ((((kk >> 3) + lq) ^ (lr & 7)) << 3);
            s16x8 af[2], bf[4];
#pragma unroll
            for (int i = 0; i < 2; ++i)
                af[i] = *(const s16x8*)&As[(wm + i * 16 + lr) * 64 + po];
#pragma unroll
            for (int j = 0; j < 4; ++j)
                bf[j] = *(const s16x8*)&Bs[(wn + j * 16 + lr) * 64 + po];
#pragma unroll
            for (int i = 0; i < 2; ++i)
#pragma unroll
                for (int j = 0; j < 4; ++j)
                    acc[i][j] = __builtin_amdgcn_mfma_f32_16x16x32_bf16(af[i], bf[j], acc[i][j], 0, 0, 0);
        }
    }
#pragma unroll
    for (int j = 0; j < 4; ++j) {
        int col = n0 + wn + j * 16 + lr;
        float bv = bias[col];
#pragma unroll
        for (int i = 0; i < 2; ++i) {
            int rowb = m0 + wm + i * 16 + lq * 4;
#pragma unroll
            for (int r = 0; r < 4; ++r)
                C[(size_t)(rowb + r) * 1024 + col] = acc[i][j][r] + bv;
        }
    }
}

// ---------------------------------------------------------------------------
extern "C" void kernel_launch(void* const* d_in, const int* in_sizes, int n_in,
                              void* d_out, int out_size, void* d_ws, size_t ws_size,
                              hipStream_t stream)
{
    (void)in_sizes; (void)n_in; (void)out_size; (void)ws_size;
    const float* x   = (const float*)d_in[0];
    const float* Wq  = (const float*)d_in[1];
    const float* bq  = (const float*)d_in[2];
    const float* Wk  = (const float*)d_in[3];
    const float* bk  = (const float*)d_in[4];
    const float* Wv  = (const float*)d_in[5];
    const float* bv  = (const float*)d_in[6];
    const float* Wp  = (const float*)d_in[7];
    const float* bp  = (const float*)d_in[8];
    const float* Wr  = (const float*)d_in[9];
    const float* br  = (const float*)d_in[10];
    const float* Ws  = (const float*)d_in[11];
    const float* bs  = (const float*)d_in[12];
    const float* temperature = (const float*)d_in[13];
    const float* qe  = (const float*)d_in[14];
    float* out = (float*)d_out;

    const size_t MB = 1048576;
    unsigned short* qb     = (unsigned short*)d_ws;                     // 8 MiB
    unsigned short* kb     = (unsigned short*)((char*)d_ws + 8 * MB);   // 8 MiB
    unsigned short* hb     = (unsigned short*)((char*)d_ws + 16 * MB);  // 8 MiB (h)
    unsigned short* wqkv   = (unsigned short*)((char*)d_ws + 24 * MB);  // 6 MiB
    unsigned short* wpb    = wqkv;                                      // reuse post-QKV
    unsigned short* wg     = (unsigned short*)((char*)d_ws + 30 * MB);  // 34 KiB
    float*          bqkv   = (float*)((char*)d_ws + 30 * MB + 65536);   // 12 KiB
    float*          logits = (float*)((char*)d_ws + 30 * MB + 131072);  // 512 KiB
    // d_out doubles as scratch until the final GEMM:
    unsigned short* xb = (unsigned short*)d_out;                        // 8 MiB
    unsigned short* vt = xb + 4 * MB;                                   // 8 MiB V^T

    dim3 blk(256);
    cvt_main<<<dim3(3605), blk, 0, stream>>>(x, Wq, Wk, Wv, Wr, Ws, bq, bk, bv,
                                             xb, wqkv, wg, bqkv);
    qkv_gemm<<<dim3(32, 24), blk, 0, stream>>>(xb, wqkv, bqkv, qb, kb, vt);
    cvt_kernel<<<dim3(512), blk, 0, stream>>>(Wp, wpb, 131072);
    attn_kernel<<<dim3(16, 32), blk, 0, stream>>>(qb, kb, vt, temperature, qe, hb);
    gl_gemm<<<dim3(32), blk, 0, stream>>>(hb, wg, logits);
    gate_apply<<<dim3(4096), blk, 0, stream>>>(hb, logits, br, bs);
    gemm64_out<<<dim3(64, 8), blk, 0, stream>>>(hb, wpb, bp, out);
}

// Round 7
// 222.954 us; speedup vs baseline: 2.0523x; 1.0771x over previous
//
#include <hip/hip_runtime.h>
#include <hip/hip_bf16.h>

typedef short s16x8 __attribute__((ext_vector_type(8)));
typedef float f32x4 __attribute__((ext_vector_type(4)));

__device__ __forceinline__ float b2f(unsigned short u) {
    union { unsigned int i; float f; } v;
    v.i = ((unsigned int)u) << 16;
    return v.f;
}
// packed fp32x2 -> bf16x2 (v_cvt_pk_bf16_f32 on gfx950); lo = a, hi = b
__device__ __forceinline__ unsigned int pkbf16(float a, float b) {
    union { __hip_bfloat162 h; unsigned int u; } v;
    v.h = __float22bfloat162_rn(make_float2(a, b));
    return v.u;
}
// raw v_exp_f32 — libm exp2f adds clamp/scale VALU (measured regression r5)
__device__ __forceinline__ float fast_exp2(float x) {
#if __has_builtin(__builtin_amdgcn_exp2f)
    return __builtin_amdgcn_exp2f(x);
#else
    return exp2f(x);
#endif
}

// async global->LDS, 16B/lane; LDS dest = wave-uniform base + lane*16
__device__ __forceinline__ void gl_lds16(const unsigned short* g, unsigned short* l) {
    __builtin_amdgcn_global_load_lds(
        (const __attribute__((address_space(1))) void*)g,
        (__attribute__((address_space(3))) void*)l, 16, 0, 0);
}

// XOR-swizzle: 16B block c of row r lives at physical block c^(r%8) (mod row width).

// ---------------------------------------------------------------------------
// Merged fp32->bf16 converts + bias pack, one launch.
// ---------------------------------------------------------------------------
__device__ __forceinline__ void cvt8(const float* __restrict__ s,
                                     unsigned short* __restrict__ d, int i) {
    const float* p = s + (size_t)i * 8;
    float4 a = *(const float4*)p;
    float4 b = *(const float4*)(p + 4);
    unsigned int u0 = pkbf16(a.x, a.y), u1 = pkbf16(a.z, a.w);
    unsigned int u2 = pkbf16(b.x, b.y), u3 = pkbf16(b.z, b.w);
    uint4 o = {u0, u1, u2, u3};
    *(uint4*)&d[(size_t)i * 8] = o;
}

__global__ __launch_bounds__(256) void cvt_main(
    const float* __restrict__ x,  const float* __restrict__ Wq,
    const float* __restrict__ Wk, const float* __restrict__ Wv,
    const float* __restrict__ Wr, const float* __restrict__ Ws,
    const float* __restrict__ bq, const float* __restrict__ bk,
    const float* __restrict__ bv,
    unsigned short* __restrict__ xb, unsigned short* __restrict__ wqkv,
    unsigned short* __restrict__ wg, float* __restrict__ bqkv)
{
    int blk = blockIdx.x, t = threadIdx.x;
    if (blk < 2048)      cvt8(x,  xb,             blk * 256 + t);
    else if (blk < 2560) cvt8(Wq, wqkv,           (blk - 2048) * 256 + t);
    else if (blk < 3072) cvt8(Wk, wqkv + 1048576, (blk - 2560) * 256 + t);
    else if (blk < 3584) cvt8(Wv, wqkv + 2097152, (blk - 3072) * 256 + t);
    else if (blk < 3592) { int i = (blk - 3584) * 256 + t; if (i < 1920) cvt8(Wr, wg, i); }
    else if (blk < 3593) { int i = t; cvt8(Ws, wg + 15360, i); }
    else {
        int i = (blk - 3593) * 256 + t;  // 0..3071
        bqkv[i] = (i < 1024) ? bq[i] : (i < 2048) ? bk[i - 1024] : bv[i - 2048];
    }
}

// standalone cvt (for Wp, launched after QKV GEMM frees its region)
__global__ __launch_bounds__(256) void cvt_kernel(
    const float* __restrict__ src, unsigned short* __restrict__ dst, int n8)
{
    int i = blockIdx.x * 256 + threadIdx.x;
    if (i < n8) cvt8(src, dst, i);
}

// ---------------------------------------------------------------------------
// QKV GEMM: C = xb[4096][1024] * Wqkv[3072][1024]^T + bias.
// 128x128 tile, BK=64, swizzled LDS + global_load_lds.
// n0<1024 -> Q; <2048 -> K; else V written transposed to Vt[b,h,d,tok].
// ---------------------------------------------------------------------------
__global__ __launch_bounds__(256) void qkv_gemm(
    const unsigned short* __restrict__ A,
    const unsigned short* __restrict__ Bw,
    const float* __restrict__ bias,
    unsigned short* __restrict__ Q, unsigned short* __restrict__ K,
    unsigned short* __restrict__ Vt)
{
    __shared__ __attribute__((aligned(16))) unsigned short As[128 * 64];
    __shared__ __attribute__((aligned(16))) unsigned short Bs[128 * 64];
    const int t = threadIdx.x;
    const int wave = t >> 6, lane = t & 63;
    const int m0 = blockIdx.x * 128, n0 = blockIdx.y * 128;
    const int wm = (wave >> 1) * 64, wn = (wave & 1) * 64;
    const int lr = lane & 15, lq = lane >> 4;
    const int srow = lane >> 3;
    const int scol = (((lane & 7) ^ srow) << 3);

    f32x4 acc[4][4];
#pragma unroll
    for (int i = 0; i < 4; ++i)
#pragma unroll
        for (int j = 0; j < 4; ++j) acc[i][j] = (f32x4){0.f, 0.f, 0.f, 0.f};

    for (int k0 = 0; k0 < 1024; k0 += 64) {
        __syncthreads();
#pragma unroll
        for (int i = 0; i < 4; ++i) {
            int rb = wave * 32 + i * 8;
            gl_lds16(&A[(size_t)(m0 + rb + srow) * 1024 + k0 + scol], &As[rb * 64]);
            gl_lds16(&Bw[(size_t)(n0 + rb + srow) * 1024 + k0 + scol], &Bs[rb * 64]);
        }
        __syncthreads();
#pragma unroll
        for (int kk = 0; kk < 64; kk += 32) {
            const int po = ((((kk >> 3) + lq) ^ (lr & 7)) << 3);
            s16x8 af[4], bf[4];
#pragma unroll
            for (int i = 0; i < 4; ++i)
                af[i] = *(const s16x8*)&As[(wm + i * 16 + lr) * 64 + po];
#pragma unroll
            for (int j = 0; j < 4; ++j)
                bf[j] = *(const s16x8*)&Bs[(wn + j * 16 + lr) * 64 + po];
#pragma unroll
            for (int i = 0; i < 4; ++i)
#pragma unroll
                for (int j = 0; j < 4; ++j)
                    acc[i][j] = __builtin_amdgcn_mfma_f32_16x16x32_bf16(af[i], bf[j], acc[i][j], 0, 0, 0);
        }
    }
    const int kind = n0 >> 10;        // 0=Q 1=K 2=V
    const int nc = n0 & 1023;
    if (kind < 2) {
        unsigned short* Cm = kind ? K : Q;
#pragma unroll
        for (int j = 0; j < 4; ++j) {
            int cl = wn + j * 16 + lr;
            float bv = bias[n0 + cl];
#pragma unroll
            for (int i = 0; i < 4; ++i) {
                int rowb = m0 + wm + i * 16 + lq * 4;
                unsigned int u0 = pkbf16(acc[i][j][0] + bv, acc[i][j][1] + bv);
                unsigned int u1 = pkbf16(acc[i][j][2] + bv, acc[i][j][3] + bv);
                Cm[(size_t)(rowb + 0) * 1024 + nc + cl] = (unsigned short)u0;
                Cm[(size_t)(rowb + 1) * 1024 + nc + cl] = (unsigned short)(u0 >> 16);
                Cm[(size_t)(rowb + 2) * 1024 + nc + cl] = (unsigned short)u1;
                Cm[(size_t)(rowb + 3) * 1024 + nc + cl] = (unsigned short)(u1 >> 16);
            }
        }
    } else {
        // V -> Vt[b,h,d,tok]: 4 consecutive tokens per lane = 8B contiguous
        const int bb = m0 >> 11;
#pragma unroll
        for (int j = 0; j < 4; ++j) {
            int col = nc + wn + j * 16 + lr;      // channel 0..1023
            int hh = col >> 6, dd = col & 63;
            float bv = bias[n0 + wn + j * 16 + lr];
#pragma unroll
            for (int i = 0; i < 4; ++i) {
                int tokb = m0 + wm + i * 16 + lq * 4;
                int tloc = tokb & 2047;
                uint2 u;
                u.x = pkbf16(acc[i][j][0] + bv, acc[i][j][1] + bv);
                u.y = pkbf16(acc[i][j][2] + bv, acc[i][j][3] + bv);
                *(uint2*)&Vt[((size_t)(bb * 16 + hh) * 64 + dd) * 2048 + tloc] = u;
            }
        }
    }
}

// ---------------------------------------------------------------------------
// Flash attention, 128-q tile, Q-fragments held in REGISTERS (q-scale fused,
// applied in-register), 128-key staging chunks computed in two 64-key halves.
// Ks region doubles as Q staging buffer (union). m=0 softmax, deferred
// l-reduce, swizzled LDS, Ps wave-private.
// ---------------------------------------------------------------------------
__global__ __launch_bounds__(256) void attn_kernel(
    const unsigned short* __restrict__ Q,   // raw q [B*N][C]
    const unsigned short* __restrict__ Kb,  // [B*N][C]
    const unsigned short* __restrict__ Vt,  // [B][H][64][N]
    const float* __restrict__ temp,
    const float* __restrict__ qe,
    unsigned short* __restrict__ Hout)      // [B*N][C]
{
    __shared__ __attribute__((aligned(16))) unsigned short Ks[128 * 64];  // 16 KB (also Q staging)
    __shared__ __attribute__((aligned(16))) unsigned short Vs[64 * 128];  // 16 KB
    __shared__ __attribute__((aligned(16))) unsigned short Ps[128 * 72];  // 18 KB
    const int t = threadIdx.x, wave = t >> 6, lane = t & 63;
    const int lr = lane & 15, lq = lane >> 4;
    const int bh = blockIdx.y, b = bh >> 4, h = bh & 15;
    const int q0 = blockIdx.x * 128;
    const int srow = lane >> 3;
    const int scol = (((lane & 7) ^ srow) << 3);

    // ---- prologue: stage raw Q (swizzled) into Ks region
#pragma unroll
    for (int i = 0; i < 4; ++i) {
        int rb = wave * 32 + i * 8;
        gl_lds16(&Q[(size_t)(b * 2048 + q0 + rb + srow) * 1024 + h * 64 + scol], &Ks[rb * 64]);
    }
    __syncthreads();

    // q' = (q/||q|| + qe[h]) * softplus(temp[h]) / (8 ln2), into registers.
    // Lane holds rows wave*32+i*16+lr (i=0,1), elems kk*32+lq*8..+7 (kk=0,1).
    // Row norm: reduce across the 4 lq-lanes (lane bits 4,5).
    float tv = temp[h];
    float sp = ((tv > 20.f) ? tv : log1pf(__expf(tv))) * 0.18033688f;
    s16x8 aq[2][2];
#pragma unroll
    for (int i = 0; i < 2; ++i) {
        float v[2][8];
        float ss = 0.f;
#pragma unroll
        for (int kk = 0; kk < 2; ++kk) {
            const int po = (((kk * 4 + lq) ^ (lr & 7)) << 3);
            s16x8 f = *(const s16x8*)&Ks[(wave * 32 + i * 16 + lr) * 64 + po];
#pragma unroll
            for (int e = 0; e < 8; ++e) {
                v[kk][e] = b2f((unsigned short)f[e]);
                ss += v[kk][e] * v[kk][e];
            }
        }
        ss += __shfl_xor(ss, 16); ss += __shfl_xor(ss, 32);
        float rn = rsqrtf(ss);
#pragma unroll
        for (int kk = 0; kk < 2; ++kk) {
            const float* qh = qe + h * 64 + kk * 32 + lq * 8;
#pragma unroll
            for (int e = 0; e < 8; e += 2) {
                unsigned int u = pkbf16((v[kk][e] * rn + qh[e]) * sp,
                                        (v[kk][e + 1] * rn + qh[e + 1]) * sp);
                aq[i][kk][e] = (short)u; aq[i][kk][e + 1] = (short)(u >> 16);
            }
        }
    }

    f32x4 accO[2][4];
#pragma unroll
    for (int i = 0; i < 2; ++i)
#pragma unroll
        for (int j = 0; j < 4; ++j) accO[i][j] = (f32x4){0.f, 0.f, 0.f, 0.f};
    float lsum[2][4] = {{0.f, 0.f, 0.f, 0.f}, {0.f, 0.f, 0.f, 0.f}};

    for (int kc = 0; kc < 2048; kc += 128) {
        __syncthreads();  // prior reads (Q-frags on iter 0 / K,V on others) done
        // stage K: 128 key-rows x 64 d (wave stages 32 rows)
#pragma unroll
        for (int i = 0; i < 4; ++i) {
            int rb = wave * 32 + i * 8;
            gl_lds16(&Kb[(size_t)(b * 2048 + kc + rb + srow) * 1024 + h * 64 + scol], &Ks[rb * 64]);
        }
        // stage V: 64 d-rows x 128 keys (wave stages 16 rows; 4 rows/instr)
#pragma unroll
        for (int i = 0; i < 4; ++i) {
            int rb = wave * 16 + i * 4;
            int vrow = rb + (lane >> 4);
            int vcb = lane & 15;
            gl_lds16(&Vt[((size_t)(b * 16 + h) * 64 + vrow) * 2048 + kc + ((vcb ^ (vrow & 7)) << 3)],
                     &Vs[rb * 128]);
        }
        __syncthreads();

#pragma unroll
        for (int half = 0; half < 2; ++half) {
            // S = Q*K^T (32 q-rows x 64 keys per wave)
            f32x4 s[2][4];
#pragma unroll
            for (int i = 0; i < 2; ++i)
#pragma unroll
                for (int j = 0; j < 4; ++j) s[i][j] = (f32x4){0.f, 0.f, 0.f, 0.f};
#pragma unroll
            for (int kk = 0; kk < 2; ++kk) {
                const int po = (((kk * 4 + lq) ^ (lr & 7)) << 3);
                s16x8 bk[4];
#pragma unroll
                for (int j = 0; j < 4; ++j)
                    bk[j] = *(const s16x8*)&Ks[(half * 64 + j * 16 + lr) * 64 + po];
#pragma unroll
                for (int i = 0; i < 2; ++i)
#pragma unroll
                    for (int j = 0; j < 4; ++j)
                        s[i][j] = __builtin_amdgcn_mfma_f32_16x16x32_bf16(aq[i][kk], bk[j], s[i][j], 0, 0, 0);
            }

            // p = 2^s; packed bf16 into Ps (wave-private rows)
#pragma unroll
            for (int i = 0; i < 2; ++i)
#pragma unroll
                for (int r = 0; r < 4; ++r) {
                    float p0 = fast_exp2(s[i][0][r]), p1 = fast_exp2(s[i][1][r]);
                    float p2 = fast_exp2(s[i][2][r]), p3 = fast_exp2(s[i][3][r]);
                    lsum[i][r] += (p0 + p1) + (p2 + p3);
                    unsigned int ua = pkbf16(p0, p1), ub = pkbf16(p2, p3);
                    int base = (wave * 32 + i * 16 + lq * 4 + r) * 72 + lr;
                    Ps[base]      = (unsigned short)ua;
                    Ps[base + 16] = (unsigned short)(ua >> 16);
                    Ps[base + 32] = (unsigned short)ub;
                    Ps[base + 48] = (unsigned short)(ub >> 16);
                }

            // O += P * V  (same-wave LDS ordering; no barrier)
#pragma unroll
            for (int kk = 0; kk < 2; ++kk) {
                const int vb = (((half * 8 + kk * 4 + lq) ^ (lr & 7)) << 3);
                s16x8 ap[2], bv[4];
#pragma unroll
                for (int i = 0; i < 2; ++i)
                    ap[i] = *(const s16x8*)&Ps[(wave * 32 + i * 16 + lr) * 72 + kk * 32 + lq * 8];
#pragma unroll
                for (int j = 0; j < 4; ++j)
                    bv[j] = *(const s16x8*)&Vs[(j * 16 + lr) * 128 + vb];
#pragma unroll
                for (int i = 0; i < 2; ++i)
#pragma unroll
                    for (int j = 0; j < 4; ++j)
                        accO[i][j] = __builtin_amdgcn_mfma_f32_16x16x32_bf16(ap[i], bv[j], accO[i][j], 0, 0, 0);
            }
        }
    }

#pragma unroll
    for (int i = 0; i < 2; ++i)
#pragma unroll
        for (int r = 0; r < 4; ++r) {
            float l = lsum[i][r];
            l += __shfl_xor(l, 1); l += __shfl_xor(l, 2);
            l += __shfl_xor(l, 4); l += __shfl_xor(l, 8);
            float inv = 1.f / l;
            int row = q0 + wave * 32 + i * 16 + lq * 4 + r;
            size_t ob = (size_t)(b * 2048 + row) * 1024 + h * 64 + lr;
            unsigned int u0 = pkbf16(accO[i][0][r] * inv, accO[i][1][r] * inv);
            unsigned int u1 = pkbf16(accO[i][2][r] * inv, accO[i][3][r] * inv);
            Hout[ob]      = (unsigned short)u0;
            Hout[ob + 16] = (unsigned short)(u0 >> 16);
            Hout[ob + 32] = (unsigned short)u1;
            Hout[ob + 48] = (unsigned short)(u1 >> 16);
        }
}

// ---------------------------------------------------------------------------
// gate_g: g[tok] = 2*sw0 + 6*sw1*top3sum from logits = h*Wg^T + bias.
// Grid 256: 16 tokens/block; per-wave K-split (wave w: k = it*256 + w*64),
// cross-wave reduce in LDS, 16 threads finish serially.
// ---------------------------------------------------------------------------
__global__ __launch_bounds__(256) void gate_g(
    const unsigned short* __restrict__ Hb,   // raw h [4096][1024]
    const unsigned short* __restrict__ Wg,   // rows 0..16 bf16
    const float* __restrict__ br, const float* __restrict__ bs,
    float* __restrict__ g)
{
    __shared__ __attribute__((aligned(16))) unsigned short As[4][16 * 64];
    __shared__ __attribute__((aligned(16))) unsigned short Gs[4][32 * 64];
    __shared__ float Lred[4][16][32];
    const int t = threadIdx.x, wave = t >> 6, lane = t & 63;
    const int lr = lane & 15, lq = lane >> 4;
    const int m0 = blockIdx.x * 16;
    const int srow = lane >> 3;
    const int scol = (((lane & 7) ^ srow) << 3);

    f32x4 acc[2];
    acc[0] = (f32x4){0.f, 0.f, 0.f, 0.f};
    acc[1] = (f32x4){0.f, 0.f, 0.f, 0.f};

    for (int k0 = wave * 64; k0 < 1024; k0 += 256) {
        gl_lds16(&Hb[(size_t)(m0 + srow) * 1024 + k0 + scol], &As[wave][0]);
        gl_lds16(&Hb[(size_t)(m0 + 8 + srow) * 1024 + k0 + scol], &As[wave][8 * 64]);
#pragma unroll
        for (int i = 0; i < 4; ++i) {
            int row = i * 8 + srow;
            int wr = (row > 16) ? 16 : row;   // clamp: rows 17..31 unused
            gl_lds16(&Wg[(size_t)wr * 1024 + k0 + scol], &Gs[wave][i * 8 * 64]);
        }
        __syncthreads();   // uniform trip count across waves
#pragma unroll
        for (int kk = 0; kk < 64; kk += 32) {
            const int po = ((((kk >> 3) + lq) ^ (lr & 7)) << 3);
            s16x8 af = *(const s16x8*)&As[wave][lr * 64 + po];
#pragma unroll
            for (int j = 0; j < 2; ++j) {
                s16x8 gf = *(const s16x8*)&Gs[wave][(j * 16 + lr) * 64 + po];
                acc[j] = __builtin_amdgcn_mfma_f32_16x16x32_bf16(af, gf, acc[j], 0, 0, 0);
            }
        }
    }
#pragma unroll
    for (int j = 0; j < 2; ++j)
#pragma unroll
        for (int r = 0; r < 4; ++r)
            Lred[wave][lq * 4 + r][j * 16 + lr] = acc[j][r];
    __syncthreads();
    if (t < 16) {
        float lg[17];
#pragma unroll
        for (int j = 0; j < 17; ++j)
            lg[j] = Lred[0][t][j] + Lred[1][t][j] + Lred[2][t][j] + Lred[3][t][j]
                  + ((j < 15) ? br[j] : bs[j - 15]);
        float mx = lg[0];
#pragma unroll
        for (int j = 1; j < 15; ++j) mx = fmaxf(mx, lg[j]);
        float sum = 0.f, v1 = -1.f, v2 = -1.f, v3 = -1.f;
#pragma unroll
        for (int j = 0; j < 15; ++j) {
            float e = __expf(lg[j] - mx);
            sum += e;
            if (e > v1)      { v3 = v2; v2 = v1; v1 = e; }
            else if (e > v2) { v3 = v2; v2 = e; }
            else if (e > v3) { v3 = e; }
        }
        float tops = (v1 + v2 + v3) / sum;
        float sm = fmaxf(lg[15], lg[16]);
        float e0 = __expf(lg[15] - sm), e1 = __expf(lg[16] - sm);
        float inv = 1.f / (e0 + e1);
        g[m0 + t] = 2.f * (e0 * inv) + 6.f * (e1 * inv) * tops;
    }
}

// ---------------------------------------------------------------------------
// Out-proj GEMM: out[m][:] = g[m] * (h·Wp^T)[m][:] + bp   (row-scale commutes)
// 64x128 tile, grid 512 = 2 blocks/CU.
// ---------------------------------------------------------------------------
__global__ __launch_bounds__(256) void gemm64_out(
    const unsigned short* __restrict__ A,
    const unsigned short* __restrict__ Bw,
    const float* __restrict__ bias,
    const float* __restrict__ g,
    float* __restrict__ C)
{
    __shared__ __attribute__((aligned(16))) unsigned short As[64 * 64];
    __shared__ __attribute__((aligned(16))) unsigned short Bs[128 * 64];
    const int t = threadIdx.x, wave = t >> 6, lane = t & 63;
    const int lr = lane & 15, lq = lane >> 4;
    const int m0 = blockIdx.x * 64, n0 = blockIdx.y * 128;
    const int wm = (wave >> 1) * 32, wn = (wave & 1) * 64;
    const int srow = lane >> 3;
    const int scol = (((lane & 7) ^ srow) << 3);

    f32x4 acc[2][4];
#pragma unroll
    for (int i = 0; i < 2; ++i)
#pragma unroll
        for (int j = 0; j < 4; ++j) acc[i][j] = (f32x4){0.f, 0.f, 0.f, 0.f};

    for (int k0 = 0; k0 < 1024; k0 += 64) {
        __syncthreads();
#pragma unroll
        for (int i = 0; i < 2; ++i) {
            int rb = wave * 16 + i * 8;
            gl_lds16(&A[(size_t)(m0 + rb + srow) * 1024 + k0 + scol], &As[rb * 64]);
        }
#pragma unroll
        for (int i = 0; i < 4; ++i) {
            int rb = wave * 32 + i * 8;
            gl_lds16(&Bw[(size_t)(n0 + rb + srow) * 1024 + k0 + scol], &Bs[rb * 64]);
        }
        __syncthreads();
#pragma unroll
        for (int kk = 0; kk < 64; kk += 32) {
            const int po = ((((kk >> 3) + lq) ^ (lr & 7)) << 3);
            s16x8 af[2], bf[4];
#pragma unroll
            for (int i = 0; i < 2; ++i)
                af[i] = *(const s16x8*)&As[(wm + i * 16 + lr) * 64 + po];
#pragma unroll
            for (int j = 0; j < 4; ++j)
                bf[j] = *(const s16x8*)&Bs[(wn + j * 16 + lr) * 64 + po];
#pragma unroll
            for (int i = 0; i < 2; ++i)
#pragma unroll
                for (int j = 0; j < 4; ++j)
                    acc[i][j] = __builtin_amdgcn_mfma_f32_16x16x32_bf16(af[i], bf[j], acc[i][j], 0, 0, 0);
        }
    }
#pragma unroll
    for (int i = 0; i < 2; ++i) {
        const float4 gi = *(const float4*)&g[m0 + wm + i * 16 + lq * 4];
        float gv[4] = {gi.x, gi.y, gi.z, gi.w};
#pragma unroll
        for (int j = 0; j < 4; ++j) {
            int col = n0 + wn + j * 16 + lr;
            float bv = bias[col];
            int rowb = m0 + wm + i * 16 + lq * 4;
#pragma unroll
            for (int r = 0; r < 4; ++r)
                C[(size_t)(rowb + r) * 1024 + col] = acc[i][j][r] * gv[r] + bv;
        }
    }
}

// ---------------------------------------------------------------------------
extern "C" void kernel_launch(void* const* d_in, const int* in_sizes, int n_in,
                              void* d_out, int out_size, void* d_ws, size_t ws_size,
                              hipStream_t stream)
{
    (void)in_sizes; (void)n_in; (void)out_size; (void)ws_size;
    const float* x   = (const float*)d_in[0];
    const float* Wq  = (const float*)d_in[1];
    const float* bq  = (const float*)d_in[2];
    const float* Wk  = (const float*)d_in[3];
    const float* bk  = (const float*)d_in[4];
    const float* Wv  = (const float*)d_in[5];
    const float* bv  = (const float*)d_in[6];
    const float* Wp  = (const float*)d_in[7];
    const float* bp  = (const float*)d_in[8];
    const float* Wr  = (const float*)d_in[9];
    const float* br  = (const float*)d_in[10];
    const float* Ws  = (const float*)d_in[11];
    const float* bs  = (const float*)d_in[12];
    const float* temperature = (const float*)d_in[13];
    const float* qe  = (const float*)d_in[14];
    float* out = (float*)d_out;

    const size_t MB = 1048576;
    unsigned short* qb   = (unsigned short*)d_ws;                     // 8 MiB
    unsigned short* kb   = (unsigned short*)((char*)d_ws + 8 * MB);   // 8 MiB
    unsigned short* hb   = (unsigned short*)((char*)d_ws + 16 * MB);  // 8 MiB (raw h)
    unsigned short* wqkv = (unsigned short*)((char*)d_ws + 24 * MB);  // 6 MiB
    unsigned short* wpb  = wqkv;                                      // reuse post-QKV
    unsigned short* wg   = (unsigned short*)((char*)d_ws + 30 * MB);  // 34 KiB
    float*          bqkv = (float*)((char*)d_ws + 30 * MB + 65536);   // 12 KiB
    float*          gbuf = (float*)((char*)d_ws + 30 * MB + 131072);  // 16 KiB
    // d_out doubles as scratch until the final GEMM:
    unsigned short* xb = (unsigned short*)d_out;                      // 8 MiB
    unsigned short* vt = xb + 4 * MB;                                 // 8 MiB V^T

    dim3 blk(256);
    cvt_main<<<dim3(3605), blk, 0, stream>>>(x, Wq, Wk, Wv, Wr, Ws, bq, bk, bv,
                                             xb, wqkv, wg, bqkv);
    qkv_gemm<<<dim3(32, 24), blk, 0, stream>>>(xb, wqkv, bqkv, qb, kb, vt);
    cvt_kernel<<<dim3(512), blk, 0, stream>>>(Wp, wpb, 131072);
    attn_kernel<<<dim3(16, 32), blk, 0, stream>>>(qb, kb, vt, temperature, qe, hb);
    gate_g<<<dim3(256), blk, 0, stream>>>(hb, wg, br, bs, gbuf);
    gemm64_out<<<dim3(64, 8), blk, 0, stream>>>(hb, wpb, bp, gbuf, out);
}

// Round 8
// 218.895 us; speedup vs baseline: 2.0903x; 1.0185x over previous
//
#include <hip/hip_runtime.h>
#include <hip/hip_bf16.h>

typedef short s16x8 __attribute__((ext_vector_type(8)));
typedef float f32x4 __attribute__((ext_vector_type(4)));

__device__ __forceinline__ float b2f(unsigned short u) {
    union { unsigned int i; float f; } v;
    v.i = ((unsigned int)u) << 16;
    return v.f;
}
// packed fp32x2 -> bf16x2 (v_cvt_pk_bf16_f32 on gfx950); lo = a, hi = b
__device__ __forceinline__ unsigned int pkbf16(float a, float b) {
    union { __hip_bfloat162 h; unsigned int u; } v;
    v.h = __float22bfloat162_rn(make_float2(a, b));
    return v.u;
}
// raw v_exp_f32 — libm exp2f adds clamp/scale VALU (measured regression r5)
__device__ __forceinline__ float fast_exp2(float x) {
#if __has_builtin(__builtin_amdgcn_exp2f)
    return __builtin_amdgcn_exp2f(x);
#else
    return exp2f(x);
#endif
}

// async global->LDS, 16B/lane; LDS dest = wave-uniform base + lane*16
__device__ __forceinline__ void gl_lds16(const unsigned short* g, unsigned short* l) {
    __builtin_amdgcn_global_load_lds(
        (const __attribute__((address_space(1))) void*)g,
        (__attribute__((address_space(3))) void*)l, 16, 0, 0);
}

// XOR-swizzle: 16B block c of row r lives at physical block c^(r%8) (mod row width).

// ---------------------------------------------------------------------------
// Merged fp32->bf16 converts + bias pack, one launch.
// ---------------------------------------------------------------------------
__device__ __forceinline__ void cvt8(const float* __restrict__ s,
                                     unsigned short* __restrict__ d, int i) {
    const float* p = s + (size_t)i * 8;
    float4 a = *(const float4*)p;
    float4 b = *(const float4*)(p + 4);
    unsigned int u0 = pkbf16(a.x, a.y), u1 = pkbf16(a.z, a.w);
    unsigned int u2 = pkbf16(b.x, b.y), u3 = pkbf16(b.z, b.w);
    uint4 o = {u0, u1, u2, u3};
    *(uint4*)&d[(size_t)i * 8] = o;
}

__global__ __launch_bounds__(256) void cvt_main(
    const float* __restrict__ x,  const float* __restrict__ Wq,
    const float* __restrict__ Wk, const float* __restrict__ Wv,
    const float* __restrict__ Wr, const float* __restrict__ Ws,
    const float* __restrict__ bq, const float* __restrict__ bk,
    const float* __restrict__ bv,
    unsigned short* __restrict__ xb, unsigned short* __restrict__ wqkv,
    unsigned short* __restrict__ wg, float* __restrict__ bqkv)
{
    int blk = blockIdx.x, t = threadIdx.x;
    if (blk < 2048)      cvt8(x,  xb,             blk * 256 + t);
    else if (blk < 2560) cvt8(Wq, wqkv,           (blk - 2048) * 256 + t);
    else if (blk < 3072) cvt8(Wk, wqkv + 1048576, (blk - 2560) * 256 + t);
    else if (blk < 3584) cvt8(Wv, wqkv + 2097152, (blk - 3072) * 256 + t);
    else if (blk < 3592) { int i = (blk - 3584) * 256 + t; if (i < 1920) cvt8(Wr, wg, i); }
    else if (blk < 3593) { int i = t; cvt8(Ws, wg + 15360, i); }
    else {
        int i = (blk - 3593) * 256 + t;  // 0..3071
        bqkv[i] = (i < 1024) ? bq[i] : (i < 2048) ? bk[i - 1024] : bv[i - 2048];
    }
}

// standalone cvt (for Wp, launched after QKV GEMM frees its region)
__global__ __launch_bounds__(256) void cvt_kernel(
    const float* __restrict__ src, unsigned short* __restrict__ dst, int n8)
{
    int i = blockIdx.x * 256 + threadIdx.x;
    if (i < n8) cvt8(src, dst, i);
}

// ---------------------------------------------------------------------------
// QKV GEMM: C = xb[4096][1024] * Wqkv[3072][1024]^T + bias.
// 128x128 tile, BK=64, swizzled LDS + global_load_lds.
// n0<1024 -> Q; <2048 -> K; else V written transposed to Vt[b,h,d,tok].
// grid x=m (32): same-m blocks land on one XCD (32 % 8 == 0) — A-tile L2 reuse.
// ---------------------------------------------------------------------------
__global__ __launch_bounds__(256) void qkv_gemm(
    const unsigned short* __restrict__ A,
    const unsigned short* __restrict__ Bw,
    const float* __restrict__ bias,
    unsigned short* __restrict__ Q, unsigned short* __restrict__ K,
    unsigned short* __restrict__ Vt)
{
    __shared__ __attribute__((aligned(16))) unsigned short As[128 * 64];
    __shared__ __attribute__((aligned(16))) unsigned short Bs[128 * 64];
    const int t = threadIdx.x;
    const int wave = t >> 6, lane = t & 63;
    const int m0 = blockIdx.x * 128, n0 = blockIdx.y * 128;
    const int wm = (wave >> 1) * 64, wn = (wave & 1) * 64;
    const int lr = lane & 15, lq = lane >> 4;
    const int srow = lane >> 3;
    const int scol = (((lane & 7) ^ srow) << 3);

    f32x4 acc[4][4];
#pragma unroll
    for (int i = 0; i < 4; ++i)
#pragma unroll
        for (int j = 0; j < 4; ++j) acc[i][j] = (f32x4){0.f, 0.f, 0.f, 0.f};

    for (int k0 = 0; k0 < 1024; k0 += 64) {
        __syncthreads();
#pragma unroll
        for (int i = 0; i < 4; ++i) {
            int rb = wave * 32 + i * 8;
            gl_lds16(&A[(size_t)(m0 + rb + srow) * 1024 + k0 + scol], &As[rb * 64]);
            gl_lds16(&Bw[(size_t)(n0 + rb + srow) * 1024 + k0 + scol], &Bs[rb * 64]);
        }
        __syncthreads();
#pragma unroll
        for (int kk = 0; kk < 64; kk += 32) {
            const int po = ((((kk >> 3) + lq) ^ (lr & 7)) << 3);
            s16x8 af[4], bf[4];
#pragma unroll
            for (int i = 0; i < 4; ++i)
                af[i] = *(const s16x8*)&As[(wm + i * 16 + lr) * 64 + po];
#pragma unroll
            for (int j = 0; j < 4; ++j)
                bf[j] = *(const s16x8*)&Bs[(wn + j * 16 + lr) * 64 + po];
#pragma unroll
            for (int i = 0; i < 4; ++i)
#pragma unroll
                for (int j = 0; j < 4; ++j)
                    acc[i][j] = __builtin_amdgcn_mfma_f32_16x16x32_bf16(af[i], bf[j], acc[i][j], 0, 0, 0);
        }
    }
    const int kind = n0 >> 10;        // 0=Q 1=K 2=V
    const int nc = n0 & 1023;
    if (kind < 2) {
        unsigned short* Cm = kind ? K : Q;
#pragma unroll
        for (int j = 0; j < 4; ++j) {
            int cl = wn + j * 16 + lr;
            float bv = bias[n0 + cl];
#pragma unroll
            for (int i = 0; i < 4; ++i) {
                int rowb = m0 + wm + i * 16 + lq * 4;
                unsigned int u0 = pkbf16(acc[i][j][0] + bv, acc[i][j][1] + bv);
                unsigned int u1 = pkbf16(acc[i][j][2] + bv, acc[i][j][3] + bv);
                Cm[(size_t)(rowb + 0) * 1024 + nc + cl] = (unsigned short)u0;
                Cm[(size_t)(rowb + 1) * 1024 + nc + cl] = (unsigned short)(u0 >> 16);
                Cm[(size_t)(rowb + 2) * 1024 + nc + cl] = (unsigned short)u1;
                Cm[(size_t)(rowb + 3) * 1024 + nc + cl] = (unsigned short)(u1 >> 16);
            }
        }
    } else {
        // V -> Vt[b,h,d,tok]: 4 consecutive tokens per lane = 8B contiguous
        const int bb = m0 >> 11;
#pragma unroll
        for (int j = 0; j < 4; ++j) {
            int col = nc + wn + j * 16 + lr;      // channel 0..1023
            int hh = col >> 6, dd = col & 63;
            float bv = bias[n0 + wn + j * 16 + lr];
#pragma unroll
            for (int i = 0; i < 4; ++i) {
                int tokb = m0 + wm + i * 16 + lq * 4;
                int tloc = tokb & 2047;
                uint2 u;
                u.x = pkbf16(acc[i][j][0] + bv, acc[i][j][1] + bv);
                u.y = pkbf16(acc[i][j][2] + bv, acc[i][j][3] + bv);
                *(uint2*)&Vt[((size_t)(bb * 16 + hh) * 64 + dd) * 2048 + tloc] = u;
            }
        }
    }
}

// ---------------------------------------------------------------------------
// Flash attention, 128-q tile, Q-fragments in registers (q-scale fused),
// 128-key staging chunks in two 64-key halves, m=0 softmax, deferred
// l-reduce, swizzled LDS, Ps wave-private.
// Grid (bh=32, qtile=16): all q-tiles of one head on one XCD (bh % 8) —
// K/V L2 locality.
// ---------------------------------------------------------------------------
__global__ __launch_bounds__(256) void attn_kernel(
    const unsigned short* __restrict__ Q,   // raw q [B*N][C]
    const unsigned short* __restrict__ Kb,  // [B*N][C]
    const unsigned short* __restrict__ Vt,  // [B][H][64][N]
    const float* __restrict__ temp,
    const float* __restrict__ qe,
    unsigned short* __restrict__ Hout)      // [B*N][C]
{
    __shared__ __attribute__((aligned(16))) unsigned short Ks[128 * 64];  // 16 KB (also Q staging)
    __shared__ __attribute__((aligned(16))) unsigned short Vs[64 * 128];  // 16 KB
    __shared__ __attribute__((aligned(16))) unsigned short Ps[128 * 72];  // 18 KB
    const int t = threadIdx.x, wave = t >> 6, lane = t & 63;
    const int lr = lane & 15, lq = lane >> 4;
    const int bh = blockIdx.x, b = bh >> 4, h = bh & 15;
    const int q0 = blockIdx.y * 128;
    const int srow = lane >> 3;
    const int scol = (((lane & 7) ^ srow) << 3);

    // ---- prologue: stage raw Q (swizzled) into Ks region
#pragma unroll
    for (int i = 0; i < 4; ++i) {
        int rb = wave * 32 + i * 8;
        gl_lds16(&Q[(size_t)(b * 2048 + q0 + rb + srow) * 1024 + h * 64 + scol], &Ks[rb * 64]);
    }
    __syncthreads();

    // q' = (q/||q|| + qe[h]) * softplus(temp[h]) / (8 ln2), into registers.
    float tv = temp[h];
    float sp = ((tv > 20.f) ? tv : log1pf(__expf(tv))) * 0.18033688f;
    s16x8 aq[2][2];
#pragma unroll
    for (int i = 0; i < 2; ++i) {
        float v[2][8];
        float ss = 0.f;
#pragma unroll
        for (int kk = 0; kk < 2; ++kk) {
            const int po = (((kk * 4 + lq) ^ (lr & 7)) << 3);
            s16x8 f = *(const s16x8*)&Ks[(wave * 32 + i * 16 + lr) * 64 + po];
#pragma unroll
            for (int e = 0; e < 8; ++e) {
                v[kk][e] = b2f((unsigned short)f[e]);
                ss += v[kk][e] * v[kk][e];
            }
        }
        ss += __shfl_xor(ss, 16); ss += __shfl_xor(ss, 32);
        float rn = rsqrtf(ss);
#pragma unroll
        for (int kk = 0; kk < 2; ++kk) {
            const float* qh = qe + h * 64 + kk * 32 + lq * 8;
#pragma unroll
            for (int e = 0; e < 8; e += 2) {
                unsigned int u = pkbf16((v[kk][e] * rn + qh[e]) * sp,
                                        (v[kk][e + 1] * rn + qh[e + 1]) * sp);
                aq[i][kk][e] = (short)u; aq[i][kk][e + 1] = (short)(u >> 16);
            }
        }
    }

    f32x4 accO[2][4];
#pragma unroll
    for (int i = 0; i < 2; ++i)
#pragma unroll
        for (int j = 0; j < 4; ++j) accO[i][j] = (f32x4){0.f, 0.f, 0.f, 0.f};
    float lsum[2][4] = {{0.f, 0.f, 0.f, 0.f}, {0.f, 0.f, 0.f, 0.f}};

    for (int kc = 0; kc < 2048; kc += 128) {
        __syncthreads();  // prior reads (Q-frags on iter 0 / K,V on others) done
        // stage K: 128 key-rows x 64 d (wave stages 32 rows)
#pragma unroll
        for (int i = 0; i < 4; ++i) {
            int rb = wave * 32 + i * 8;
            gl_lds16(&Kb[(size_t)(b * 2048 + kc + rb + srow) * 1024 + h * 64 + scol], &Ks[rb * 64]);
        }
        // stage V: 64 d-rows x 128 keys (wave stages 16 rows; 4 rows/instr)
#pragma unroll
        for (int i = 0; i < 4; ++i) {
            int rb = wave * 16 + i * 4;
            int vrow = rb + (lane >> 4);
            int vcb = lane & 15;
            gl_lds16(&Vt[((size_t)(b * 16 + h) * 64 + vrow) * 2048 + kc + ((vcb ^ (vrow & 7)) << 3)],
                     &Vs[rb * 128]);
        }
        __syncthreads();

#pragma unroll
        for (int half = 0; half < 2; ++half) {
            // S = Q*K^T (32 q-rows x 64 keys per wave)
            f32x4 s[2][4];
#pragma unroll
            for (int i = 0; i < 2; ++i)
#pragma unroll
                for (int j = 0; j < 4; ++j) s[i][j] = (f32x4){0.f, 0.f, 0.f, 0.f};
#pragma unroll
            for (int kk = 0; kk < 2; ++kk) {
                const int po = (((kk * 4 + lq) ^ (lr & 7)) << 3);
                s16x8 bk[4];
#pragma unroll
                for (int j = 0; j < 4; ++j)
                    bk[j] = *(const s16x8*)&Ks[(half * 64 + j * 16 + lr) * 64 + po];
#pragma unroll
                for (int i = 0; i < 2; ++i)
#pragma unroll
                    for (int j = 0; j < 4; ++j)
                        s[i][j] = __builtin_amdgcn_mfma_f32_16x16x32_bf16(aq[i][kk], bk[j], s[i][j], 0, 0, 0);
            }

            // p = 2^s; packed bf16 into Ps (wave-private rows)
#pragma unroll
            for (int i = 0; i < 2; ++i)
#pragma unroll
                for (int r = 0; r < 4; ++r) {
                    float p0 = fast_exp2(s[i][0][r]), p1 = fast_exp2(s[i][1][r]);
                    float p2 = fast_exp2(s[i][2][r]), p3 = fast_exp2(s[i][3][r]);
                    lsum[i][r] += (p0 + p1) + (p2 + p3);
                    unsigned int ua = pkbf16(p0, p1), ub = pkbf16(p2, p3);
                    int base = (wave * 32 + i * 16 + lq * 4 + r) * 72 + lr;
                    Ps[base]      = (unsigned short)ua;
                    Ps[base + 16] = (unsigned short)(ua >> 16);
                    Ps[base + 32] = (unsigned short)ub;
                    Ps[base + 48] = (unsigned short)(ub >> 16);
                }

            // O += P * V  (same-wave LDS ordering; no barrier)
#pragma unroll
            for (int kk = 0; kk < 2; ++kk) {
                const int vb = (((half * 8 + kk * 4 + lq) ^ (lr & 7)) << 3);
                s16x8 ap[2], bv[4];
#pragma unroll
                for (int i = 0; i < 2; ++i)
                    ap[i] = *(const s16x8*)&Ps[(wave * 32 + i * 16 + lr) * 72 + kk * 32 + lq * 8];
#pragma unroll
                for (int j = 0; j < 4; ++j)
                    bv[j] = *(const s16x8*)&Vs[(j * 16 + lr) * 128 + vb];
#pragma unroll
                for (int i = 0; i < 2; ++i)
#pragma unroll
                    for (int j = 0; j < 4; ++j)
                        accO[i][j] = __builtin_amdgcn_mfma_f32_16x16x32_bf16(ap[i], bv[j], accO[i][j], 0, 0, 0);
            }
        }
    }

#pragma unroll
    for (int i = 0; i < 2; ++i)
#pragma unroll
        for (int r = 0; r < 4; ++r) {
            float l = lsum[i][r];
            l += __shfl_xor(l, 1); l += __shfl_xor(l, 2);
            l += __shfl_xor(l, 4); l += __shfl_xor(l, 8);
            float inv = 1.f / l;
            int row = q0 + wave * 32 + i * 16 + lq * 4 + r;
            size_t ob = (size_t)(b * 2048 + row) * 1024 + h * 64 + lr;
            unsigned int u0 = pkbf16(accO[i][0][r] * inv, accO[i][1][r] * inv);
            unsigned int u1 = pkbf16(accO[i][2][r] * inv, accO[i][3][r] * inv);
            Hout[ob]      = (unsigned short)u0;
            Hout[ob + 16] = (unsigned short)(u0 >> 16);
            Hout[ob + 32] = (unsigned short)u1;
            Hout[ob + 48] = (unsigned short)(u1 >> 16);
        }
}

// ---------------------------------------------------------------------------
// gate_g: g[tok] = 2*sw0 + 6*sw1*top3sum from logits = h*Wg^T + bias.
// ---------------------------------------------------------------------------
__global__ __launch_bounds__(256) void gate_g(
    const unsigned short* __restrict__ Hb,   // raw h [4096][1024]
    const unsigned short* __restrict__ Wg,   // rows 0..16 bf16
    const float* __restrict__ br, const float* __restrict__ bs,
    float* __restrict__ g)
{
    __shared__ __attribute__((aligned(16))) unsigned short As[4][16 * 64];
    __shared__ __attribute__((aligned(16))) unsigned short Gs[4][32 * 64];
    __shared__ float Lred[4][16][32];
    const int t = threadIdx.x, wave = t >> 6, lane = t & 63;
    const int lr = lane & 15, lq = lane >> 4;
    const int m0 = blockIdx.x * 16;
    const int srow = lane >> 3;
    const int scol = (((lane & 7) ^ srow) << 3);

    f32x4 acc[2];
    acc[0] = (f32x4){0.f, 0.f, 0.f, 0.f};
    acc[1] = (f32x4){0.f, 0.f, 0.f, 0.f};

    for (int k0 = wave * 64; k0 < 1024; k0 += 256) {
        gl_lds16(&Hb[(size_t)(m0 + srow) * 1024 + k0 + scol], &As[wave][0]);
        gl_lds16(&Hb[(size_t)(m0 + 8 + srow) * 1024 + k0 + scol], &As[wave][8 * 64]);
#pragma unroll
        for (int i = 0; i < 4; ++i) {
            int row = i * 8 + srow;
            int wr = (row > 16) ? 16 : row;   // clamp: rows 17..31 unused
            gl_lds16(&Wg[(size_t)wr * 1024 + k0 + scol], &Gs[wave][i * 8 * 64]);
        }
        __syncthreads();   // uniform trip count across waves
#pragma unroll
        for (int kk = 0; kk < 64; kk += 32) {
            const int po = ((((kk >> 3) + lq) ^ (lr & 7)) << 3);
            s16x8 af = *(const s16x8*)&As[wave][lr * 64 + po];
#pragma unroll
            for (int j = 0; j < 2; ++j) {
                s16x8 gf = *(const s16x8*)&Gs[wave][(j * 16 + lr) * 64 + po];
                acc[j] = __builtin_amdgcn_mfma_f32_16x16x32_bf16(af, gf, acc[j], 0, 0, 0);
            }
        }
    }
#pragma unroll
    for (int j = 0; j < 2; ++j)
#pragma unroll
        for (int r = 0; r < 4; ++r)
            Lred[wave][lq * 4 + r][j * 16 + lr] = acc[j][r];
    __syncthreads();
    if (t < 16) {
        float lg[17];
#pragma unroll
        for (int j = 0; j < 17; ++j)
            lg[j] = Lred[0][t][j] + Lred[1][t][j] + Lred[2][t][j] + Lred[3][t][j]
                  + ((j < 15) ? br[j] : bs[j - 15]);
        float mx = lg[0];
#pragma unroll
        for (int j = 1; j < 15; ++j) mx = fmaxf(mx, lg[j]);
        float sum = 0.f, v1 = -1.f, v2 = -1.f, v3 = -1.f;
#pragma unroll
        for (int j = 0; j < 15; ++j) {
            float e = __expf(lg[j] - mx);
            sum += e;
            if (e > v1)      { v3 = v2; v2 = v1; v1 = e; }
            else if (e > v2) { v3 = v2; v2 = e; }
            else if (e > v3) { v3 = e; }
        }
        float tops = (v1 + v2 + v3) / sum;
        float sm = fmaxf(lg[15], lg[16]);
        float e0 = __expf(lg[15] - sm), e1 = __expf(lg[16] - sm);
        float inv = 1.f / (e0 + e1);
        g[m0 + t] = 2.f * (e0 * inv) + 6.f * (e1 * inv) * tops;
    }
}

// ---------------------------------------------------------------------------
// Out-proj GEMM: out[m][:] = g[m] * (h·Wp^T)[m][:] + bp   (row-scale commutes)
// 64x64 tile, grid 1024 = 4 blocks/CU (latency overlap); 2x2 waves of 32x32.
// ---------------------------------------------------------------------------
__global__ __launch_bounds__(256) void gemm64_out(
    const unsigned short* __restrict__ A,
    const unsigned short* __restrict__ Bw,
    const float* __restrict__ bias,
    const float* __restrict__ g,
    float* __restrict__ C)
{
    __shared__ __attribute__((aligned(16))) unsigned short As[64 * 64];
    __shared__ __attribute__((aligned(16))) unsigned short Bs[64 * 64];
    const int t = threadIdx.x, wave = t >> 6, lane = t & 63;
    const int lr = lane & 15, lq = lane >> 4;
    const int m0 = blockIdx.x * 64, n0 = blockIdx.y * 64;
    const int wm = (wave >> 1) * 32, wn = (wave & 1) * 32;
    const int srow = lane >> 3;
    const int scol = (((lane & 7) ^ srow) << 3);

    f32x4 acc[2][2];
#pragma unroll
    for (int i = 0; i < 2; ++i)
#pragma unroll
        for (int j = 0; j < 2; ++j) acc[i][j] = (f32x4){0.f, 0.f, 0.f, 0.f};

    for (int k0 = 0; k0 < 1024; k0 += 64) {
        __syncthreads();
#pragma unroll
        for (int i = 0; i < 2; ++i) {
            int rb = wave * 16 + i * 8;
            gl_lds16(&A[(size_t)(m0 + rb + srow) * 1024 + k0 + scol], &As[rb * 64]);
            gl_lds16(&Bw[(size_t)(n0 + rb + srow) * 1024 + k0 + scol], &Bs[rb * 64]);
        }
        __syncthreads();
#pragma unroll
        for (int kk = 0; kk < 64; kk += 32) {
            const int po = ((((kk >> 3) + lq) ^ (lr & 7)) << 3);
            s16x8 af[2], bf[2];
#pragma unroll
            for (int i = 0; i < 2; ++i)
                af[i] = *(const s16x8*)&As[(wm + i * 16 + lr) * 64 + po];
#pragma unroll
            for (int j = 0; j < 2; ++j)
                bf[j] = *(const s16x8*)&Bs[(wn + j * 16 + lr) * 64 + po];
#pragma unroll
            for (int i = 0; i < 2; ++i)
#pragma unroll
                for (int j = 0; j < 2; ++j)
                    acc[i][j] = __builtin_amdgcn_mfma_f32_16x16x32_bf16(af[i], bf[j], acc[i][j], 0, 0, 0);
        }
    }
#pragma unroll
    for (int i = 0; i < 2; ++i) {
        const float4 gi = *(const float4*)&g[m0 + wm + i * 16 + lq * 4];
        float gv[4] = {gi.x, gi.y, gi.z, gi.w};
#pragma unroll
        for (int j = 0; j < 2; ++j) {
            int col = n0 + wn + j * 16 + lr;
            float bv = bias[col];
            int rowb = m0 + wm + i * 16 + lq * 4;
#pragma unroll
            for (int r = 0; r < 4; ++r)
                C[(size_t)(rowb + r) * 1024 + col] = acc[i][j][r] * gv[r] + bv;
        }
    }
}

// ---------------------------------------------------------------------------
extern "C" void kernel_launch(void* const* d_in, const int* in_sizes, int n_in,
                              void* d_out, int out_size, void* d_ws, size_t ws_size,
                              hipStream_t stream)
{
    (void)in_sizes; (void)n_in; (void)out_size; (void)ws_size;
    const float* x   = (const float*)d_in[0];
    const float* Wq  = (const float*)d_in[1];
    const float* bq  = (const float*)d_in[2];
    const float* Wk  = (const float*)d_in[3];
    const float* bk  = (const float*)d_in[4];
    const float* Wv  = (const float*)d_in[5];
    const float* bv  = (const float*)d_in[6];
    const float* Wp  = (const float*)d_in[7];
    const float* bp  = (const float*)d_in[8];
    const float* Wr  = (const float*)d_in[9];
    const float* br  = (const float*)d_in[10];
    const float* Ws  = (const float*)d_in[11];
    const float* bs  = (const float*)d_in[12];
    const float* temperature = (const float*)d_in[13];
    const float* qe  = (const float*)d_in[14];
    float* out = (float*)d_out;

    const size_t MB = 1048576;
    unsigned short* qb   = (unsigned short*)d_ws;                     // 8 MiB
    unsigned short* kb   = (unsigned short*)((char*)d_ws + 8 * MB);   // 8 MiB
    unsigned short* hb   = (unsigned short*)((char*)d_ws + 16 * MB);  // 8 MiB (raw h)
    unsigned short* wqkv = (unsigned short*)((char*)d_ws + 24 * MB);  // 6 MiB
    unsigned short* wpb  = wqkv;                                      // reuse post-QKV
    unsigned short* wg   = (unsigned short*)((char*)d_ws + 30 * MB);  // 34 KiB
    float*          bqkv = (float*)((char*)d_ws + 30 * MB + 65536);   // 12 KiB
    float*          gbuf = (float*)((char*)d_ws + 30 * MB + 131072);  // 16 KiB
    // d_out doubles as scratch until the final GEMM:
    unsigned short* xb = (unsigned short*)d_out;                      // 8 MiB
    unsigned short* vt = xb + 4 * MB;                                 // 8 MiB V^T

    dim3 blk(256);
    cvt_main<<<dim3(3605), blk, 0, stream>>>(x, Wq, Wk, Wv, Wr, Ws, bq, bk, bv,
                                             xb, wqkv, wg, bqkv);
    qkv_gemm<<<dim3(32, 24), blk, 0, stream>>>(xb, wqkv, bqkv, qb, kb, vt);
    cvt_kernel<<<dim3(512), blk, 0, stream>>>(Wp, wpb, 131072);
    attn_kernel<<<dim3(32, 16), blk, 0, stream>>>(qb, kb, vt, temperature, qe, hb);
    gate_g<<<dim3(256), blk, 0, stream>>>(hb, wg, br, bs, gbuf);
    gemm64_out<<<dim3(64, 16), blk, 0, stream>>>(hb, wpb, bp, gbuf, out);
}